// Round 1
// baseline (1027.187 us; speedup 1.0000x reference)
//
#include <hip/hip_runtime.h>
#include <math.h>

#define NN 12800
#define NE 204800
#define LL 24
#define HH 128
#define BB 64
#define RR 8
#define VAx 20
#define KC 1152  // R*H + H

// ---------------- small prep kernels ----------------

__global__ void k_transpose2(const float* __restrict__ W, int ld, int col0,
                             float* __restrict__ WT, int rows, int cols) {
  int idx = blockIdx.x * 256 + threadIdx.x;
  if (idx >= rows * cols) return;
  int r = idx / cols, c = idx - r * cols;
  WT[c * rows + r] = W[r * ld + col0 + c];
}

__global__ void k_embed(const int* __restrict__ nt, const float* __restrict__ emb,
                        float* __restrict__ x) {
  int idx = blockIdx.x * 256 + threadIdx.x;
  if (idx >= NN * HH) return;
  int n = idx >> 7, h = idx & 127;
  x[idx] = emb[nt[n] * HH + h];
}

__global__ void k_count(const int* __restrict__ key, int* __restrict__ cnt, int n) {
  int i = blockIdx.x * 256 + threadIdx.x;
  if (i < n) atomicAdd(&cnt[key[i]], 1);
}

// single-block exclusive scan; writes out[0..n] (out[n] = total)
__global__ void k_scan(const int* __restrict__ in, int* __restrict__ out, int n) {
  __shared__ int sh[1024];
  __shared__ int carry_s;
  if (threadIdx.x == 0) carry_s = 0;
  __syncthreads();
  for (int base = 0; base < n; base += 1024) {
    int i = base + threadIdx.x;
    int v = (i < n) ? in[i] : 0;
    sh[threadIdx.x] = v;
    __syncthreads();
    for (int off = 1; off < 1024; off <<= 1) {
      int t = (threadIdx.x >= off) ? sh[threadIdx.x - off] : 0;
      __syncthreads();
      sh[threadIdx.x] += t;
      __syncthreads();
    }
    int carry = carry_s;
    if (i < n) out[i] = carry + sh[threadIdx.x] - v;  // exclusive
    __syncthreads();
    if (threadIdx.x == 0) carry_s += sh[1023];
    __syncthreads();
  }
  if (threadIdx.x == 0) out[n] = carry_s;
}

__global__ void k_copy_i(const int* __restrict__ a, int* __restrict__ b, int n) {
  int i = blockIdx.x * 256 + threadIdx.x;
  if (i < n) b[i] = a[i];
}

__global__ void k_scatter_e(const int* __restrict__ src, const int* __restrict__ dst,
                            const int* __restrict__ rel, int* __restrict__ cur,
                            int* __restrict__ esort) {
  int e = blockIdx.x * 256 + threadIdx.x;
  if (e >= NE) return;
  int p = atomicAdd(&cur[dst[e]], 1);
  esort[p] = src[e] | (rel[e] << 16);
}

__global__ void k_scatter_b(const int* __restrict__ bs, int* __restrict__ cur,
                            int* __restrict__ bnodes) {
  int n = blockIdx.x * 256 + threadIdx.x;
  if (n >= NN) return;
  int p = atomicAdd(&cur[bs[n]], 1);
  bnodes[p] = n;
}

// ---------------- RGCN aggregation: one wave per node ----------------
// A[row, r*128+h] = mean over incoming edges of relation r of x[src,h]
// A[row, 1024+h]  = x[n, h]   (root term appended so one GEMM does everything)
__global__ __launch_bounds__(256) void k_agg(const float* __restrict__ x,
                                             const int* __restrict__ indptr,
                                             const int* __restrict__ esort,
                                             float* __restrict__ A, int n0, int nc) {
  int wid = ((blockIdx.x * 256) + threadIdx.x) >> 6;
  int lane = threadIdx.x & 63;
  if (wid >= nc) return;
  int n = n0 + wid;
  float a0=0,a1=0,a2=0,a3=0,a4=0,a5=0,a6=0,a7=0;
  float a8=0,a9=0,a10=0,a11=0,a12=0,a13=0,a14=0,a15=0;
  int c0=0,c1=0,c2=0,c3=0,c4=0,c5=0,c6=0,c7=0;
  int e0 = indptr[n], e1 = indptr[n + 1];
  for (int e = e0; e < e1; ++e) {
    int pk = esort[e];
    int s = pk & 0xFFFF;
    int r = pk >> 16;
    float v0 = x[s * HH + lane];
    float v1 = x[s * HH + 64 + lane];
    switch (r) {  // r is wave-uniform -> uniform branch, accumulators stay in VGPRs
      case 0: a0 += v0; a1 += v1; c0++; break;
      case 1: a2 += v0; a3 += v1; c1++; break;
      case 2: a4 += v0; a5 += v1; c2++; break;
      case 3: a6 += v0; a7 += v1; c3++; break;
      case 4: a8 += v0; a9 += v1; c4++; break;
      case 5: a10 += v0; a11 += v1; c5++; break;
      case 6: a12 += v0; a13 += v1; c6++; break;
      default: a14 += v0; a15 += v1; c7++; break;
    }
  }
  float* Ar = A + (size_t)wid * KC;
  float i0 = 1.0f / (float)(c0 > 0 ? c0 : 1);
  float i1 = 1.0f / (float)(c1 > 0 ? c1 : 1);
  float i2 = 1.0f / (float)(c2 > 0 ? c2 : 1);
  float i3 = 1.0f / (float)(c3 > 0 ? c3 : 1);
  float i4 = 1.0f / (float)(c4 > 0 ? c4 : 1);
  float i5 = 1.0f / (float)(c5 > 0 ? c5 : 1);
  float i6 = 1.0f / (float)(c6 > 0 ? c6 : 1);
  float i7 = 1.0f / (float)(c7 > 0 ? c7 : 1);
  Ar[0 + lane] = a0 * i0;    Ar[64 + lane] = a1 * i0;
  Ar[128 + lane] = a2 * i1;  Ar[192 + lane] = a3 * i1;
  Ar[256 + lane] = a4 * i2;  Ar[320 + lane] = a5 * i2;
  Ar[384 + lane] = a6 * i3;  Ar[448 + lane] = a7 * i3;
  Ar[512 + lane] = a8 * i4;  Ar[576 + lane] = a9 * i4;
  Ar[640 + lane] = a10 * i5; Ar[704 + lane] = a11 * i5;
  Ar[768 + lane] = a12 * i6; Ar[832 + lane] = a13 * i6;
  Ar[896 + lane] = a14 * i7; Ar[960 + lane] = a15 * i7;
  Ar[1024 + lane] = x[n * HH + lane];
  Ar[1088 + lane] = x[n * HH + 64 + lane];
}

// ---------------- generic fp32 tiled GEMM: C = A[M,K] * B[K,N] (+bias)(+relu) ----------------
template <bool BIAS, bool RELU>
__global__ __launch_bounds__(256) void k_gemm(const float* __restrict__ Am, int lda,
                                              const float* __restrict__ Bm, int ldb,
                                              const float* __restrict__ bias,
                                              float* __restrict__ C, int ldc,
                                              int M, int Nc, int K) {
  __shared__ float As[16][65];
  __shared__ float Bs[16][65];
  int m0 = blockIdx.y * 64, n0 = blockIdx.x * 64;
  int tx = threadIdx.x & 15, ty = threadIdx.x >> 4;
  float acc[4][4] = {};
  for (int k0 = 0; k0 < K; k0 += 16) {
#pragma unroll
    for (int i = 0; i < 4; ++i) {
      int idx = threadIdx.x + i * 256;
      int kk = idx & 15, mm = idx >> 4;
      int gm = m0 + mm, gk = k0 + kk;
      As[kk][mm] = (gm < M && gk < K) ? Am[(size_t)gm * lda + gk] : 0.f;
    }
#pragma unroll
    for (int i = 0; i < 4; ++i) {
      int idx = threadIdx.x + i * 256;
      int nn = idx & 63, kk = idx >> 6;
      int gk = k0 + kk, gn = n0 + nn;
      Bs[kk][nn] = (gk < K && gn < Nc) ? Bm[(size_t)gk * ldb + gn] : 0.f;
    }
    __syncthreads();
#pragma unroll
    for (int kk = 0; kk < 16; ++kk) {
      float a[4], b[4];
#pragma unroll
      for (int i = 0; i < 4; ++i) a[i] = As[kk][ty * 4 + i];
#pragma unroll
      for (int j = 0; j < 4; ++j) b[j] = Bs[kk][tx * 4 + j];
#pragma unroll
      for (int i = 0; i < 4; ++i)
#pragma unroll
        for (int j = 0; j < 4; ++j) acc[i][j] = fmaf(a[i], b[j], acc[i][j]);
    }
    __syncthreads();
  }
#pragma unroll
  for (int i = 0; i < 4; ++i) {
    int gm = m0 + ty * 4 + i;
    if (gm >= M) continue;
#pragma unroll
    for (int j = 0; j < 4; ++j) {
      int gn = n0 + tx * 4 + j;
      if (gn >= Nc) continue;
      float v = acc[i][j];
      if (BIAS) v += bias[gn];
      if (RELU) v = fmaxf(v, 0.f);
      C[(size_t)gm * ldc + gn] = v;
    }
  }
}

// ---------------- graph mean pooling ----------------
__global__ __launch_bounds__(128) void k_hG(const float* __restrict__ x,
                                            const int* __restrict__ bptr,
                                            const int* __restrict__ bnodes,
                                            float* __restrict__ hG) {
  int b = blockIdx.x, t = threadIdx.x;
  int i0 = bptr[b], i1 = bptr[b + 1];
  float s = 0.f;
  for (int i = i0; i < i1; ++i) s += x[bnodes[i] * HH + t];
  hG[b * HH + t] = s / (float)(i1 - i0);
}

// ---------------- heads ----------------
__global__ __launch_bounds__(128) void k_action(const float* __restrict__ hG,
                                                const float* __restrict__ linAT,
                                                const float* __restrict__ linA_b,
                                                const float* __restrict__ linAf_w,
                                                const float* __restrict__ linAf_b,
                                                float* __restrict__ outA) {
  int b = blockIdx.x, j = threadIdx.x;
  __shared__ float hsh[HH], t1[HH];
  hsh[j] = hG[b * HH + j];
  __syncthreads();
  float s = linA_b[j];
  for (int k = 0; k < HH; ++k) s = fmaf(hsh[k], linAT[k * HH + j], s);
  t1[j] = fmaxf(s, 0.f);
  __syncthreads();
  if (j < VAx) {
    float o = linAf_b[j];
    for (int k = 0; k < HH; ++k) o = fmaf(t1[k], linAf_w[j * HH + k], o);
    outA[b * VAx + j] = o;
  }
}

__global__ __launch_bounds__(128) void k_final(const float* __restrict__ hG,
                                               const float* __restrict__ finT,
                                               const float* __restrict__ fin_b,
                                               const float* __restrict__ finf_w,
                                               const float* __restrict__ finf_b,
                                               float* __restrict__ outF) {
  int b = blockIdx.x, j = threadIdx.x;
  __shared__ float hsh[HH], t1[HH];
  hsh[j] = hG[b * HH + j];
  __syncthreads();
  float s = fin_b[j];
  for (int k = 0; k < HH; ++k) s = fmaf(hsh[k], finT[k * HH + j], s);
  t1[j] = fmaxf(s, 0.f);
  __syncthreads();
  if (j == 0) {
    float o = finf_b[0];
    for (int k = 0; k < HH; ++k) o = fmaf(t1[k], finf_w[k], o);
    outF[b] = 1.f / (1.f + expf(-o));
  }
}

// ---------------- agg[b,l,h] = sum_{n in b} seq_in[n,l] * emb[n,h] ----------------
__global__ __launch_bounds__(256) void k_aggS(const float* __restrict__ seqin,
                                              const float* __restrict__ x,
                                              const int* __restrict__ bptr,
                                              const int* __restrict__ bnodes,
                                              float* __restrict__ aggS) {
  int b = blockIdx.x;
  int h = threadIdx.x & 127, l0 = threadIdx.x >> 7;
  float acc[12] = {};
  int i0 = bptr[b], i1 = bptr[b + 1];
  for (int i = i0; i < i1; ++i) {
    int n = bnodes[i];
    float e = x[n * HH + h];
#pragma unroll
    for (int t = 0; t < 12; ++t) {
      float s = seqin[n * LL + l0 + 2 * t];
      acc[t] = fmaf(s, e, acc[t]);
    }
  }
#pragma unroll
  for (int t = 0; t < 12; ++t) aggS[((size_t)b * LL + l0 + 2 * t) * HH + h] = acc[t];
}

__global__ void k_ig(const float* __restrict__ aggS, const float* __restrict__ embA,
                     const int* __restrict__ act, float* __restrict__ ig) {
  int idx = blockIdx.x * 256 + threadIdx.x;
  if (idx >= BB * LL * HH) return;
  int h = idx & 127;
  int bt = idx >> 7;
  int t = bt % LL, b = bt / LL;
  ig[idx] = (t == 0) ? embA[act[b] * HH + h] : aggS[((size_t)b * LL + (t - 1)) * HH + h];
}

// ---------------- GRU: one block per batch element, 24 sequential steps ----------------
__global__ __launch_bounds__(128) void k_gru(const float* __restrict__ gi,
                                             const float* __restrict__ WhhT,
                                             const float* __restrict__ bhh,
                                             const float* __restrict__ hG,
                                             float* __restrict__ seqout) {
  int b = blockIdx.x, j = threadIdx.x;
  __shared__ float h[HH];
  h[j] = hG[b * HH + j];
  __syncthreads();
  for (int t = 0; t < LL; ++t) {
    float gr = bhh[j], gz = bhh[128 + j], gn = bhh[256 + j];
#pragma unroll 4
    for (int k = 0; k < HH; ++k) {
      float hk = h[k];
      gr = fmaf(hk, WhhT[k * 384 + j], gr);
      gz = fmaf(hk, WhhT[k * 384 + 128 + j], gz);
      gn = fmaf(hk, WhhT[k * 384 + 256 + j], gn);
    }
    const float* gib = gi + ((size_t)b * LL + t) * 384;
    float r = 1.f / (1.f + expf(-(gib[j] + gr)));
    float z = 1.f / (1.f + expf(-(gib[128 + j] + gz)));
    float n = tanhf(gib[256 + j] + r * gn);
    float hn = (1.f - z) * n + z * h[j];
    __syncthreads();
    h[j] = hn;
    __syncthreads();
    seqout[((size_t)b * LL + t) * HH + j] = hn;
  }
}

// ---------------- fused logits: relu(part1[bs[n],l,:] + part2[n,:] + bN) . wNf ----------------
__global__ __launch_bounds__(256) void k_logits(const float* __restrict__ part1,
                                                const float* __restrict__ part2,
                                                const float* __restrict__ linN_b,
                                                const float* __restrict__ linNf_w,
                                                const float* __restrict__ linNf_b,
                                                const int* __restrict__ bs,
                                                float* __restrict__ logits) {
  int wid = ((blockIdx.x * 256) + threadIdx.x) >> 6;
  int lane = threadIdx.x & 63;
  if (wid >= NN) return;
  int n = wid;
  int b = bs[n];
  float p2a = part2[n * HH + lane] + linN_b[lane];
  float p2b = part2[n * HH + 64 + lane] + linN_b[64 + lane];
  float wa = linNf_w[lane], wb = linNf_w[64 + lane];
  const float* p1 = part1 + (size_t)b * LL * HH;
  float bf = linNf_b[0];
  for (int l = 0; l < LL; ++l) {
    float v = fmaxf(p1[l * HH + lane] + p2a, 0.f) * wa +
              fmaxf(p1[l * HH + 64 + lane] + p2b, 0.f) * wb;
#pragma unroll
    for (int off = 32; off > 0; off >>= 1) v += __shfl_down(v, off);
    if (lane == 0) logits[n * LL + l] = v + bf;
  }
}

// ---------------- segment softmax over nodes of each (batch, l) ----------------
__global__ __launch_bounds__(64) void k_softmax(const float* __restrict__ logits,
                                                const int* __restrict__ bptr,
                                                const int* __restrict__ bnodes,
                                                float* __restrict__ outN) {
  int b = blockIdx.x / LL, l = blockIdx.x % LL;
  int lane = threadIdx.x;
  int i0 = bptr[b], i1 = bptr[b + 1];
  float m = -1e30f;
  for (int i = i0 + lane; i < i1; i += 64) m = fmaxf(m, logits[bnodes[i] * LL + l]);
#pragma unroll
  for (int off = 32; off > 0; off >>= 1) m = fmaxf(m, __shfl_xor(m, off));
  float s = 0.f;
  for (int i = i0 + lane; i < i1; i += 64) s += expf(logits[bnodes[i] * LL + l] - m);
#pragma unroll
  for (int off = 32; off > 0; off >>= 1) s += __shfl_xor(s, off);
  float inv = 1.f / s;
  for (int i = i0 + lane; i < i1; i += 64) {
    int n = bnodes[i];
    outN[n * LL + l] = expf(logits[n * LL + l] - m) * inv;
  }
}

// ---------------- host ----------------
extern "C" void kernel_launch(void* const* d_in, const int* in_sizes, int n_in,
                              void* d_out, int out_size, void* d_ws, size_t ws_size,
                              hipStream_t stream) {
  const int* nodeTypes = (const int*)d_in[0];
  const int* esrc = (const int*)d_in[1];
  const int* edst = esrc + NE;
  const int* erel = (const int*)d_in[2];
  const int* bs = (const int*)d_in[3];
  const float* seqin = (const float*)d_in[4];
  const int* actin = (const int*)d_in[7];
  const float* embN = (const float*)d_in[8];
  const float* embA = (const float*)d_in[9];
  const float* rgcnW = (const float*)d_in[10];
  const float* rgcnRoot = (const float*)d_in[11];
  const float* rgcnB = (const float*)d_in[12];
  const float* Wih = (const float*)d_in[13];
  const float* Whh = (const float*)d_in[14];
  const float* bih = (const float*)d_in[15];
  const float* bhh = (const float*)d_in[16];
  const float* linA_w = (const float*)d_in[17];
  const float* linA_b = (const float*)d_in[18];
  const float* linAf_w = (const float*)d_in[19];
  const float* linAf_b = (const float*)d_in[20];
  const float* linN_w = (const float*)d_in[21];
  const float* linN_b = (const float*)d_in[22];
  const float* linNf_w = (const float*)d_in[23];
  const float* linNf_b = (const float*)d_in[24];
  const float* fin_w = (const float*)d_in[25];
  const float* fin_b = (const float*)d_in[26];
  const float* finf_w = (const float*)d_in[27];
  const float* finf_b = (const float*)d_in[28];

  float* outA = (float*)d_out;
  float* outNodes = outA + BB * VAx;
  float* outF = outNodes + (size_t)NN * LL;

  char* basep = (char*)d_ws;
  size_t off = 0;
  auto alloc = [&](size_t bytes) -> void* {
    void* p = basep + off;
    off = (off + bytes + 255) & ~(size_t)255;
    return p;
  };

  float* x = (float*)alloc(sizeof(float) * NN * HH);
  float* x2 = (float*)alloc(sizeof(float) * NN * HH);
  float* hG = (float*)alloc(sizeof(float) * BB * HH);
  float* Wcat = (float*)alloc(sizeof(float) * KC * HH);
  float* WihT = (float*)alloc(sizeof(float) * HH * 3 * HH);
  float* WhhT = (float*)alloc(sizeof(float) * HH * 3 * HH);
  float* linAT = (float*)alloc(sizeof(float) * HH * HH);
  float* finT = (float*)alloc(sizeof(float) * HH * HH);
  float* linN1T = (float*)alloc(sizeof(float) * HH * HH);
  float* linN2T = (float*)alloc(sizeof(float) * HH * HH);
  float* aggS = (float*)alloc(sizeof(float) * BB * LL * HH);
  float* ig = (float*)alloc(sizeof(float) * BB * LL * HH);
  float* gi = (float*)alloc(sizeof(float) * BB * LL * 3 * HH);
  float* seq = (float*)alloc(sizeof(float) * BB * LL * HH);
  float* part1 = (float*)alloc(sizeof(float) * BB * LL * HH);
  float* part2 = (float*)alloc(sizeof(float) * NN * HH);
  float* logitsB = (float*)alloc(sizeof(float) * NN * LL);
  int* deg = (int*)alloc(sizeof(int) * NN);
  int* indptr = (int*)alloc(sizeof(int) * (NN + 1));
  int* cur = (int*)alloc(sizeof(int) * NN);
  int* esort = (int*)alloc(sizeof(int) * NE);
  int* bcnt = (int*)alloc(sizeof(int) * BB);
  int* bptr = (int*)alloc(sizeof(int) * (BB + 1));
  int* bcur = (int*)alloc(sizeof(int) * BB);
  int* bnodes = (int*)alloc(sizeof(int) * NN);

  size_t remain = (ws_size > off) ? (ws_size - off) : 0;
  int NCk = NN;
  while ((size_t)NCk * KC * sizeof(float) > remain && NCk > 100) NCk >>= 1;
  float* A = (float*)alloc((size_t)NCk * KC * sizeof(float));

  // ---- prep ----
  hipMemsetAsync(deg, 0, sizeof(int) * NN, stream);
  hipMemsetAsync(bcnt, 0, sizeof(int) * BB, stream);
  hipMemcpyAsync(Wcat, rgcnW, sizeof(float) * RR * HH * HH, hipMemcpyDeviceToDevice, stream);
  hipMemcpyAsync(Wcat + RR * HH * HH, rgcnRoot, sizeof(float) * HH * HH,
                 hipMemcpyDeviceToDevice, stream);
  int g1 = (3 * HH * HH + 255) / 256;
  k_transpose2<<<g1, 256, 0, stream>>>(Wih, HH, 0, WihT, 3 * HH, HH);
  k_transpose2<<<g1, 256, 0, stream>>>(Whh, HH, 0, WhhT, 3 * HH, HH);
  int g2 = (HH * HH + 255) / 256;
  k_transpose2<<<g2, 256, 0, stream>>>(linA_w, HH, 0, linAT, HH, HH);
  k_transpose2<<<g2, 256, 0, stream>>>(fin_w, HH, 0, finT, HH, HH);
  k_transpose2<<<g2, 256, 0, stream>>>(linN_w, 2 * HH, 0, linN1T, HH, HH);
  k_transpose2<<<g2, 256, 0, stream>>>(linN_w, 2 * HH, HH, linN2T, HH, HH);
  k_embed<<<(NN * HH + 255) / 256, 256, 0, stream>>>(nodeTypes, embN, x);
  k_count<<<(NE + 255) / 256, 256, 0, stream>>>(edst, deg, NE);
  k_count<<<(NN + 255) / 256, 256, 0, stream>>>(bs, bcnt, NN);
  k_scan<<<1, 1024, 0, stream>>>(deg, indptr, NN);
  k_scan<<<1, 1024, 0, stream>>>(bcnt, bptr, BB);
  k_copy_i<<<(NN + 255) / 256, 256, 0, stream>>>(indptr, cur, NN);
  k_copy_i<<<1, 256, 0, stream>>>(bptr, bcur, BB);
  k_scatter_e<<<(NE + 255) / 256, 256, 0, stream>>>(esrc, edst, erel, cur, esort);
  k_scatter_b<<<(NN + 255) / 256, 256, 0, stream>>>(bs, bcur, bnodes);

  // ---- 2 RGCN layers (shared weights) ----
  const float* xin = x;
  float* xout = x2;
  for (int layer = 0; layer < 2; ++layer) {
    for (int n0 = 0; n0 < NN; n0 += NCk) {
      int nc = NN - n0 < NCk ? NN - n0 : NCk;
      k_agg<<<(nc + 3) / 4, 256, 0, stream>>>(xin, indptr, esort, A, n0, nc);
      dim3 g(HH / 64, (nc + 63) / 64);
      k_gemm<true, true><<<g, 256, 0, stream>>>(A, KC, Wcat, HH, rgcnB,
                                                xout + (size_t)n0 * HH, HH, nc, HH, KC);
    }
    const float* t = xin;
    xin = xout;
    xout = (float*)t;
  }
  const float* nodeEmb = xin;  // == x after two swaps

  // ---- pooling + heads ----
  k_hG<<<BB, HH, 0, stream>>>(nodeEmb, bptr, bnodes, hG);
  k_action<<<BB, HH, 0, stream>>>(hG, linAT, linA_b, linAf_w, linAf_b, outA);
  k_final<<<BB, HH, 0, stream>>>(hG, finT, fin_b, finf_w, finf_b, outF);

  // ---- GRU input ----
  k_aggS<<<BB, 256, 0, stream>>>(seqin, nodeEmb, bptr, bnodes, aggS);
  k_ig<<<(BB * LL * HH + 255) / 256, 256, 0, stream>>>(aggS, embA, actin, ig);
  {
    dim3 g((3 * HH) / 64, (BB * LL) / 64);
    k_gemm<true, false><<<g, 256, 0, stream>>>(ig, HH, WihT, 3 * HH, bih, gi, 3 * HH,
                                               BB * LL, 3 * HH, HH);
  }
  k_gru<<<BB, HH, 0, stream>>>(gi, WhhT, bhh, hG, seq);

  // ---- node logits ----
  {
    dim3 g(HH / 64, (BB * LL) / 64);
    k_gemm<false, false><<<g, 256, 0, stream>>>(seq, HH, linN1T, HH, nullptr, part1, HH,
                                                BB * LL, HH, HH);
  }
  {
    dim3 g(HH / 64, NN / 64);
    k_gemm<false, false><<<g, 256, 0, stream>>>(nodeEmb, HH, linN2T, HH, nullptr, part2,
                                                HH, NN, HH, HH);
  }
  k_logits<<<NN / 4, 256, 0, stream>>>(part1, part2, linN_b, linNf_w, linNf_b, bs, logitsB);
  k_softmax<<<BB * LL, 64, 0, stream>>>(logitsB, bptr, bnodes, outNodes);
}

// Round 2
// 675.053 us; speedup vs baseline: 1.5216x; 1.5216x over previous
//
#include <hip/hip_runtime.h>
#include <math.h>

#define NN 12800
#define NE 204800
#define LL 24
#define HH 128
#define BB 64
#define RR 8
#define VAx 20
#define KC 1152  // R*H + H

typedef __attribute__((ext_vector_type(8))) short bf16x8;
typedef __attribute__((ext_vector_type(4))) float f32x4;

__device__ inline unsigned short f2bf(float f) {
  unsigned u = __float_as_uint(f);
  unsigned r = u + 0x7FFF + ((u >> 16) & 1);  // RNE
  return (unsigned short)(r >> 16);
}
__device__ inline float bf2f(unsigned short s) {
  return __uint_as_float(((unsigned)s) << 16);
}

// ---------------- small prep kernels ----------------

__global__ void k_transpose2(const float* __restrict__ W, int ld, int col0,
                             float* __restrict__ WT, int rows, int cols) {
  int idx = blockIdx.x * 256 + threadIdx.x;
  if (idx >= rows * cols) return;
  int r = idx / cols, c = idx - r * cols;
  WT[c * rows + r] = W[r * ld + col0 + c];
}

// WcatT[d][k] bf16 : k<1024 -> rgcnW[r=k>>7][h=k&127][d], else root[k-1024][d]
__global__ void k_prep_wcatT(const float* __restrict__ W, const float* __restrict__ root,
                             unsigned short* __restrict__ BT) {
  int idx = blockIdx.x * 256 + threadIdx.x;
  if (idx >= HH * KC) return;
  int d = idx / KC, k = idx - d * KC;
  float v = (k < 1024) ? W[(k >> 7) * (HH * HH) + (k & 127) * HH + d]
                       : root[(k - 1024) * HH + d];
  BT[idx] = f2bf(v);
}

// BT[d][k] bf16 = W[d*ld + col0 + k], 128x128
__global__ void k_prep_bt128(const float* __restrict__ W, int ld, int col0,
                             unsigned short* __restrict__ BT) {
  int idx = blockIdx.x * 256 + threadIdx.x;
  if (idx >= HH * HH) return;
  int d = idx >> 7, k = idx & 127;
  BT[idx] = f2bf(W[d * ld + col0 + k]);
}

// x (bf16 packed pairs) from embedding
__global__ void k_embed(const int* __restrict__ nt, const float* __restrict__ emb,
                        unsigned int* __restrict__ x) {
  int idx = blockIdx.x * 256 + threadIdx.x;
  if (idx >= NN * 64) return;
  int n = idx >> 6, p = idx & 63;
  const float* e = emb + (size_t)nt[n] * HH + p * 2;
  x[idx] = (unsigned)f2bf(e[0]) | ((unsigned)f2bf(e[1]) << 16);
}

__global__ void k_count(const int* __restrict__ key, int* __restrict__ cnt, int n) {
  int i = blockIdx.x * 256 + threadIdx.x;
  if (i < n) atomicAdd(&cnt[key[i]], 1);
}

// single-block exclusive scan; writes out[0..n] (out[n] = total)
__global__ void k_scan(const int* __restrict__ in, int* __restrict__ out, int n) {
  __shared__ int sh[1024];
  __shared__ int carry_s;
  if (threadIdx.x == 0) carry_s = 0;
  __syncthreads();
  for (int base = 0; base < n; base += 1024) {
    int i = base + threadIdx.x;
    int v = (i < n) ? in[i] : 0;
    sh[threadIdx.x] = v;
    __syncthreads();
    for (int off = 1; off < 1024; off <<= 1) {
      int t = (threadIdx.x >= off) ? sh[threadIdx.x - off] : 0;
      __syncthreads();
      sh[threadIdx.x] += t;
      __syncthreads();
    }
    int carry = carry_s;
    if (i < n) out[i] = carry + sh[threadIdx.x] - v;  // exclusive
    __syncthreads();
    if (threadIdx.x == 0) carry_s += sh[1023];
    __syncthreads();
  }
  if (threadIdx.x == 0) out[n] = carry_s;
}

__global__ void k_copy_i(const int* __restrict__ a, int* __restrict__ b, int n) {
  int i = blockIdx.x * 256 + threadIdx.x;
  if (i < n) b[i] = a[i];
}

__global__ void k_scatter_e(const int* __restrict__ src, const int* __restrict__ dst,
                            const int* __restrict__ rel, int* __restrict__ cur,
                            int* __restrict__ esort) {
  int e = blockIdx.x * 256 + threadIdx.x;
  if (e >= NE) return;
  int p = atomicAdd(&cur[dst[e]], 1);
  esort[p] = src[e] | (rel[e] << 16);
}

__global__ void k_scatter_b(const int* __restrict__ bs, int* __restrict__ cur,
                            int* __restrict__ bnodes) {
  int n = blockIdx.x * 256 + threadIdx.x;
  if (n >= NN) return;
  int p = atomicAdd(&cur[bs[n]], 1);
  bnodes[p] = n;
}

// ---------------- RGCN aggregation: one wave per node (bf16 x, bf16 A) ----------------
// lane owns feature pair h = {2*lane, 2*lane+1}
__global__ __launch_bounds__(256) void k_agg(const unsigned int* __restrict__ x,
                                             const int* __restrict__ indptr,
                                             const int* __restrict__ esort,
                                             unsigned int* __restrict__ A, int n0, int nc) {
  int wid = ((blockIdx.x * 256) + threadIdx.x) >> 6;
  int lane = threadIdx.x & 63;
  if (wid >= nc) return;
  int n = n0 + wid;
  float a0=0,a1=0,a2=0,a3=0,a4=0,a5=0,a6=0,a7=0;
  float b0=0,b1=0,b2=0,b3=0,b4=0,b5=0,b6=0,b7=0;
  int c0=0,c1=0,c2=0,c3=0,c4=0,c5=0,c6=0,c7=0;
  int e0 = indptr[n], e1 = indptr[n + 1];
  for (int e = e0; e < e1; ++e) {
    int pk = esort[e];
    int s = pk & 0xFFFF;
    int r = pk >> 16;
    unsigned v = x[s * 64 + lane];
    float v0 = bf2f((unsigned short)(v & 0xFFFF));
    float v1 = bf2f((unsigned short)(v >> 16));
    switch (r) {  // wave-uniform branch
      case 0: a0 += v0; b0 += v1; c0++; break;
      case 1: a1 += v0; b1 += v1; c1++; break;
      case 2: a2 += v0; b2 += v1; c2++; break;
      case 3: a3 += v0; b3 += v1; c3++; break;
      case 4: a4 += v0; b4 += v1; c4++; break;
      case 5: a5 += v0; b5 += v1; c5++; break;
      case 6: a6 += v0; b6 += v1; c6++; break;
      default: a7 += v0; b7 += v1; c7++; break;
    }
  }
  unsigned int* Ar = A + (size_t)wid * (KC / 2);
  float i0 = 1.0f / (float)(c0 > 0 ? c0 : 1);
  float i1 = 1.0f / (float)(c1 > 0 ? c1 : 1);
  float i2 = 1.0f / (float)(c2 > 0 ? c2 : 1);
  float i3 = 1.0f / (float)(c3 > 0 ? c3 : 1);
  float i4 = 1.0f / (float)(c4 > 0 ? c4 : 1);
  float i5 = 1.0f / (float)(c5 > 0 ? c5 : 1);
  float i6 = 1.0f / (float)(c6 > 0 ? c6 : 1);
  float i7 = 1.0f / (float)(c7 > 0 ? c7 : 1);
#define PACK(lo, hi) ((unsigned)f2bf(lo) | ((unsigned)f2bf(hi) << 16))
  Ar[0 * 64 + lane] = PACK(a0 * i0, b0 * i0);
  Ar[1 * 64 + lane] = PACK(a1 * i1, b1 * i1);
  Ar[2 * 64 + lane] = PACK(a2 * i2, b2 * i2);
  Ar[3 * 64 + lane] = PACK(a3 * i3, b3 * i3);
  Ar[4 * 64 + lane] = PACK(a4 * i4, b4 * i4);
  Ar[5 * 64 + lane] = PACK(a5 * i5, b5 * i5);
  Ar[6 * 64 + lane] = PACK(a6 * i6, b6 * i6);
  Ar[7 * 64 + lane] = PACK(a7 * i7, b7 * i7);
#undef PACK
  Ar[512 + lane] = x[n * 64 + lane];  // root term
}

// ---------------- bf16 MFMA GEMM: C[M,128] = A[M,K](bf16) * B[K,128] ----------------
// BT is B transposed, [128][K] bf16 row-major. BM=64 (4 waves x 16 rows), BK=64.
// LDS XOR-swizzle (row&7)<<4 applied by pre-swizzling per-lane GLOBAL source;
// LDS dest stays linear (global_load_lds constraint).
// OUTMODE 0: fp32 store, no bias. OUTMODE 1: bias+relu, bf16 store.
template <int OUTMODE>
__global__ __launch_bounds__(256) void k_mgemm(const unsigned short* __restrict__ Abf, int lda,
                                               const unsigned short* __restrict__ BTbf, int ldb,
                                               const float* __restrict__ bias,
                                               void* __restrict__ C, int M, int K) {
  __shared__ unsigned int ldsu[(8192 + 16384) / 4];
  char* ldsc = (char*)ldsu;
  int tid = threadIdx.x;
  int m0 = blockIdx.x * 64;
  int w = tid >> 6, l = tid & 63;
  int lrow = l & 15, lg = l >> 4;
  f32x4 acc[8] = {};

  const char* Ab = (const char*)Abf;
  const char* Bb = (const char*)BTbf;
  int KT = K >> 6;
  for (int kt = 0; kt < KT; ++kt) {
    int k0 = kt << 6;
    // stage A tile [64][64] -> lds[0..8192)
#pragma unroll
    for (int i = 0; i < 2; ++i) {
      int slot = i * 256 + tid;
      int row = slot >> 3;
      int colb = (slot & 7) << 4;
      int gr = m0 + row;
      gr = gr < M ? gr : M - 1;
      size_t srcb = ((size_t)gr * lda + k0) * 2 + (size_t)(colb ^ ((row & 7) << 4));
      __builtin_amdgcn_global_load_lds((const unsigned int*)(Ab + srcb),
                                       (unsigned int*)(ldsc + slot * 16), 16, 0, 0);
    }
    // stage BT tile [128][64] -> lds[8192..24576)
#pragma unroll
    for (int i = 0; i < 4; ++i) {
      int slot = i * 256 + tid;
      int row = slot >> 3;
      int colb = (slot & 7) << 4;
      size_t srcb = ((size_t)row * ldb + k0) * 2 + (size_t)(colb ^ ((row & 7) << 4));
      __builtin_amdgcn_global_load_lds((const unsigned int*)(Bb + srcb),
                                       (unsigned int*)(ldsc + 8192 + slot * 16), 16, 0, 0);
    }
    __syncthreads();
#pragma unroll
    for (int h = 0; h < 2; ++h) {
      int arow = w * 16 + lrow;
      bf16x8 af = *(const bf16x8*)(ldsc + arow * 128 +
                                   ((h * 64 + lg * 16) ^ ((arow & 7) << 4)));
#pragma unroll
      for (int c = 0; c < 8; ++c) {
        int brow = c * 16 + lrow;
        bf16x8 bf = *(const bf16x8*)(ldsc + 8192 + brow * 128 +
                                     ((h * 64 + lg * 16) ^ ((brow & 7) << 4)));
        acc[c] = __builtin_amdgcn_mfma_f32_16x16x32_bf16(af, bf, acc[c], 0, 0, 0);
      }
    }
    __syncthreads();
  }
  // epilogue: lane holds D[m = w*16 + lg*4 + r][n = c*16 + lrow]
#pragma unroll
  for (int c = 0; c < 8; ++c) {
#pragma unroll
    for (int r = 0; r < 4; ++r) {
      int gm = m0 + w * 16 + lg * 4 + r;
      if (gm >= M) continue;
      int gn = c * 16 + lrow;
      float v = acc[c][r];
      if (OUTMODE == 1) {
        v = fmaxf(v + bias[gn], 0.f);
        ((unsigned short*)C)[(size_t)gm * HH + gn] = f2bf(v);
      } else {
        ((float*)C)[(size_t)gm * HH + gn] = v;
      }
    }
  }
}

// ---------------- generic fp32 tiled GEMM (kept for small GEMMs) ----------------
template <bool BIAS, bool RELU>
__global__ __launch_bounds__(256) void k_gemm(const float* __restrict__ Am, int lda,
                                              const float* __restrict__ Bm, int ldb,
                                              const float* __restrict__ bias,
                                              float* __restrict__ C, int ldc,
                                              int M, int Nc, int K) {
  __shared__ float As[16][65];
  __shared__ float Bs[16][65];
  int m0 = blockIdx.y * 64, n0 = blockIdx.x * 64;
  int tx = threadIdx.x & 15, ty = threadIdx.x >> 4;
  float acc[4][4] = {};
  for (int k0 = 0; k0 < K; k0 += 16) {
#pragma unroll
    for (int i = 0; i < 4; ++i) {
      int idx = threadIdx.x + i * 256;
      int kk = idx & 15, mm = idx >> 4;
      int gm = m0 + mm, gk = k0 + kk;
      As[kk][mm] = (gm < M && gk < K) ? Am[(size_t)gm * lda + gk] : 0.f;
    }
#pragma unroll
    for (int i = 0; i < 4; ++i) {
      int idx = threadIdx.x + i * 256;
      int nn = idx & 63, kk = idx >> 6;
      int gk = k0 + kk, gn = n0 + nn;
      Bs[kk][nn] = (gk < K && gn < Nc) ? Bm[(size_t)gk * ldb + gn] : 0.f;
    }
    __syncthreads();
#pragma unroll
    for (int kk = 0; kk < 16; ++kk) {
      float a[4], b[4];
#pragma unroll
      for (int i = 0; i < 4; ++i) a[i] = As[kk][ty * 4 + i];
#pragma unroll
      for (int j = 0; j < 4; ++j) b[j] = Bs[kk][tx * 4 + j];
#pragma unroll
      for (int i = 0; i < 4; ++i)
#pragma unroll
        for (int j = 0; j < 4; ++j) acc[i][j] = fmaf(a[i], b[j], acc[i][j]);
    }
    __syncthreads();
  }
#pragma unroll
  for (int i = 0; i < 4; ++i) {
    int gm = m0 + ty * 4 + i;
    if (gm >= M) continue;
#pragma unroll
    for (int j = 0; j < 4; ++j) {
      int gn = n0 + tx * 4 + j;
      if (gn >= Nc) continue;
      float v = acc[i][j];
      if (BIAS) v += bias[gn];
      if (RELU) v = fmaxf(v, 0.f);
      C[(size_t)gm * ldc + gn] = v;
    }
  }
}

// ---------------- graph mean pooling (bf16 in, fp32 out) ----------------
__global__ __launch_bounds__(128) void k_hG(const unsigned short* __restrict__ x,
                                            const int* __restrict__ bptr,
                                            const int* __restrict__ bnodes,
                                            float* __restrict__ hG) {
  int b = blockIdx.x, t = threadIdx.x;
  int i0 = bptr[b], i1 = bptr[b + 1];
  float s = 0.f;
  for (int i = i0; i < i1; ++i) s += bf2f(x[bnodes[i] * HH + t]);
  hG[b * HH + t] = s / (float)(i1 - i0);
}

// ---------------- heads ----------------
__global__ __launch_bounds__(128) void k_action(const float* __restrict__ hG,
                                                const float* __restrict__ linAT,
                                                const float* __restrict__ linA_b,
                                                const float* __restrict__ linAf_w,
                                                const float* __restrict__ linAf_b,
                                                float* __restrict__ outA) {
  int b = blockIdx.x, j = threadIdx.x;
  __shared__ float hsh[HH], t1[HH];
  hsh[j] = hG[b * HH + j];
  __syncthreads();
  float s = linA_b[j];
  for (int k = 0; k < HH; ++k) s = fmaf(hsh[k], linAT[k * HH + j], s);
  t1[j] = fmaxf(s, 0.f);
  __syncthreads();
  if (j < VAx) {
    float o = linAf_b[j];
    for (int k = 0; k < HH; ++k) o = fmaf(t1[k], linAf_w[j * HH + k], o);
    outA[b * VAx + j] = o;
  }
}

__global__ __launch_bounds__(128) void k_final(const float* __restrict__ hG,
                                               const float* __restrict__ finT,
                                               const float* __restrict__ fin_b,
                                               const float* __restrict__ finf_w,
                                               const float* __restrict__ finf_b,
                                               float* __restrict__ outF) {
  int b = blockIdx.x, j = threadIdx.x;
  __shared__ float hsh[HH], t1[HH];
  hsh[j] = hG[b * HH + j];
  __syncthreads();
  float s = fin_b[j];
  for (int k = 0; k < HH; ++k) s = fmaf(hsh[k], finT[k * HH + j], s);
  t1[j] = fmaxf(s, 0.f);
  __syncthreads();
  if (j == 0) {
    float o = finf_b[0];
    for (int k = 0; k < HH; ++k) o = fmaf(t1[k], finf_w[k], o);
    outF[b] = 1.f / (1.f + expf(-o));
  }
}

// ---------------- agg[b,l,h] = sum_{n in b} seq_in[n,l] * emb[n,h] (bf16 emb) ----------------
__global__ __launch_bounds__(256) void k_aggS(const float* __restrict__ seqin,
                                              const unsigned short* __restrict__ x,
                                              const int* __restrict__ bptr,
                                              const int* __restrict__ bnodes,
                                              float* __restrict__ aggS) {
  int b = blockIdx.x;
  int h = threadIdx.x & 127, l0 = threadIdx.x >> 7;
  float acc[12] = {};
  int i0 = bptr[b], i1 = bptr[b + 1];
  for (int i = i0; i < i1; ++i) {
    int n = bnodes[i];
    float e = bf2f(x[n * HH + h]);
#pragma unroll
    for (int t = 0; t < 12; ++t) {
      float s = seqin[n * LL + l0 + 2 * t];
      acc[t] = fmaf(s, e, acc[t]);
    }
  }
#pragma unroll
  for (int t = 0; t < 12; ++t) aggS[((size_t)b * LL + l0 + 2 * t) * HH + h] = acc[t];
}

__global__ void k_ig(const float* __restrict__ aggS, const float* __restrict__ embA,
                     const int* __restrict__ act, float* __restrict__ ig) {
  int idx = blockIdx.x * 256 + threadIdx.x;
  if (idx >= BB * LL * HH) return;
  int h = idx & 127;
  int bt = idx >> 7;
  int t = bt % LL, b = bt / LL;
  ig[idx] = (t == 0) ? embA[act[b] * HH + h] : aggS[((size_t)b * LL + (t - 1)) * HH + h];
}

// ---------------- GRU ----------------
__global__ __launch_bounds__(128) void k_gru(const float* __restrict__ gi,
                                             const float* __restrict__ WhhT,
                                             const float* __restrict__ bhh,
                                             const float* __restrict__ hG,
                                             float* __restrict__ seqout) {
  int b = blockIdx.x, j = threadIdx.x;
  __shared__ float h[HH];
  h[j] = hG[b * HH + j];
  __syncthreads();
  for (int t = 0; t < LL; ++t) {
    float gr = bhh[j], gz = bhh[128 + j], gn = bhh[256 + j];
#pragma unroll 4
    for (int k = 0; k < HH; ++k) {
      float hk = h[k];
      gr = fmaf(hk, WhhT[k * 384 + j], gr);
      gz = fmaf(hk, WhhT[k * 384 + 128 + j], gz);
      gn = fmaf(hk, WhhT[k * 384 + 256 + j], gn);
    }
    const float* gib = gi + ((size_t)b * LL + t) * 384;
    float r = 1.f / (1.f + expf(-(gib[j] + gr)));
    float z = 1.f / (1.f + expf(-(gib[128 + j] + gz)));
    float n = tanhf(gib[256 + j] + r * gn);
    float hn = (1.f - z) * n + z * h[j];
    __syncthreads();
    h[j] = hn;
    __syncthreads();
    seqout[((size_t)b * LL + t) * HH + j] = hn;
  }
}

// ---------------- fused logits ----------------
__global__ __launch_bounds__(256) void k_logits(const float* __restrict__ part1,
                                                const float* __restrict__ part2,
                                                const float* __restrict__ linN_b,
                                                const float* __restrict__ linNf_w,
                                                const float* __restrict__ linNf_b,
                                                const int* __restrict__ bs,
                                                float* __restrict__ logits) {
  int wid = ((blockIdx.x * 256) + threadIdx.x) >> 6;
  int lane = threadIdx.x & 63;
  if (wid >= NN) return;
  int n = wid;
  int b = bs[n];
  float p2a = part2[n * HH + lane] + linN_b[lane];
  float p2b = part2[n * HH + 64 + lane] + linN_b[64 + lane];
  float wa = linNf_w[lane], wb = linNf_w[64 + lane];
  const float* p1 = part1 + (size_t)b * LL * HH;
  float bf = linNf_b[0];
  for (int l = 0; l < LL; ++l) {
    float v = fmaxf(p1[l * HH + lane] + p2a, 0.f) * wa +
              fmaxf(p1[l * HH + 64 + lane] + p2b, 0.f) * wb;
#pragma unroll
    for (int off = 32; off > 0; off >>= 1) v += __shfl_down(v, off);
    if (lane == 0) logits[n * LL + l] = v + bf;
  }
}

// ---------------- segment softmax ----------------
__global__ __launch_bounds__(64) void k_softmax(const float* __restrict__ logits,
                                                const int* __restrict__ bptr,
                                                const int* __restrict__ bnodes,
                                                float* __restrict__ outN) {
  int b = blockIdx.x / LL, l = blockIdx.x % LL;
  int lane = threadIdx.x;
  int i0 = bptr[b], i1 = bptr[b + 1];
  float m = -1e30f;
  for (int i = i0 + lane; i < i1; i += 64) m = fmaxf(m, logits[bnodes[i] * LL + l]);
#pragma unroll
  for (int off = 32; off > 0; off >>= 1) m = fmaxf(m, __shfl_xor(m, off));
  float s = 0.f;
  for (int i = i0 + lane; i < i1; i += 64) s += expf(logits[bnodes[i] * LL + l] - m);
#pragma unroll
  for (int off = 32; off > 0; off >>= 1) s += __shfl_xor(s, off);
  float inv = 1.f / s;
  for (int i = i0 + lane; i < i1; i += 64) {
    int n = bnodes[i];
    outN[n * LL + l] = expf(logits[n * LL + l] - m) * inv;
  }
}

// ---------------- host ----------------
extern "C" void kernel_launch(void* const* d_in, const int* in_sizes, int n_in,
                              void* d_out, int out_size, void* d_ws, size_t ws_size,
                              hipStream_t stream) {
  const int* nodeTypes = (const int*)d_in[0];
  const int* esrc = (const int*)d_in[1];
  const int* edst = esrc + NE;
  const int* erel = (const int*)d_in[2];
  const int* bs = (const int*)d_in[3];
  const float* seqin = (const float*)d_in[4];
  const int* actin = (const int*)d_in[7];
  const float* embN = (const float*)d_in[8];
  const float* embA = (const float*)d_in[9];
  const float* rgcnW = (const float*)d_in[10];
  const float* rgcnRoot = (const float*)d_in[11];
  const float* rgcnB = (const float*)d_in[12];
  const float* Wih = (const float*)d_in[13];
  const float* Whh = (const float*)d_in[14];
  const float* bih = (const float*)d_in[15];
  const float* bhh = (const float*)d_in[16];
  const float* linA_w = (const float*)d_in[17];
  const float* linA_b = (const float*)d_in[18];
  const float* linAf_w = (const float*)d_in[19];
  const float* linAf_b = (const float*)d_in[20];
  const float* linN_w = (const float*)d_in[21];
  const float* linN_b = (const float*)d_in[22];
  const float* linNf_w = (const float*)d_in[23];
  const float* linNf_b = (const float*)d_in[24];
  const float* fin_w = (const float*)d_in[25];
  const float* fin_b = (const float*)d_in[26];
  const float* finf_w = (const float*)d_in[27];
  const float* finf_b = (const float*)d_in[28];

  float* outA = (float*)d_out;
  float* outNodes = outA + BB * VAx;
  float* outF = outNodes + (size_t)NN * LL;

  char* basep = (char*)d_ws;
  size_t off = 0;
  auto alloc = [&](size_t bytes) -> void* {
    void* p = basep + off;
    off = (off + bytes + 255) & ~(size_t)255;
    return p;
  };

  unsigned int* x = (unsigned int*)alloc(sizeof(unsigned int) * NN * 64);   // bf16 pairs
  unsigned int* x2 = (unsigned int*)alloc(sizeof(unsigned int) * NN * 64);  // bf16 pairs
  float* hG = (float*)alloc(sizeof(float) * BB * HH);
  unsigned short* wcatT = (unsigned short*)alloc(sizeof(unsigned short) * HH * KC);
  unsigned short* linN2bt = (unsigned short*)alloc(sizeof(unsigned short) * HH * HH);
  float* WihT = (float*)alloc(sizeof(float) * HH * 3 * HH);
  float* WhhT = (float*)alloc(sizeof(float) * HH * 3 * HH);
  float* linAT = (float*)alloc(sizeof(float) * HH * HH);
  float* finT = (float*)alloc(sizeof(float) * HH * HH);
  float* linN1T = (float*)alloc(sizeof(float) * HH * HH);
  float* aggS = (float*)alloc(sizeof(float) * BB * LL * HH);
  float* ig = (float*)alloc(sizeof(float) * BB * LL * HH);
  float* gi = (float*)alloc(sizeof(float) * BB * LL * 3 * HH);
  float* seq = (float*)alloc(sizeof(float) * BB * LL * HH);
  float* part1 = (float*)alloc(sizeof(float) * BB * LL * HH);
  float* part2 = (float*)alloc(sizeof(float) * NN * HH);
  float* logitsB = (float*)alloc(sizeof(float) * NN * LL);
  int* deg = (int*)alloc(sizeof(int) * NN);
  int* indptr = (int*)alloc(sizeof(int) * (NN + 1));
  int* cur = (int*)alloc(sizeof(int) * NN);
  int* esort = (int*)alloc(sizeof(int) * NE);
  int* bcnt = (int*)alloc(sizeof(int) * BB);
  int* bptr = (int*)alloc(sizeof(int) * (BB + 1));
  int* bcur = (int*)alloc(sizeof(int) * BB);
  int* bnodes = (int*)alloc(sizeof(int) * NN);

  size_t remain = (ws_size > off) ? (ws_size - off) : 0;
  int NCk = NN;
  while ((size_t)NCk * KC * 2 > remain && NCk > 100) NCk >>= 1;
  unsigned int* A = (unsigned int*)alloc((size_t)NCk * (KC / 2) * sizeof(unsigned int));

  // ---- prep ----
  hipMemsetAsync(deg, 0, sizeof(int) * NN, stream);
  hipMemsetAsync(bcnt, 0, sizeof(int) * BB, stream);
  k_prep_wcatT<<<(HH * KC + 255) / 256, 256, 0, stream>>>(rgcnW, rgcnRoot, wcatT);
  k_prep_bt128<<<(HH * HH + 255) / 256, 256, 0, stream>>>(linN_w, 2 * HH, HH, linN2bt);
  int g1 = (3 * HH * HH + 255) / 256;
  k_transpose2<<<g1, 256, 0, stream>>>(Wih, HH, 0, WihT, 3 * HH, HH);
  k_transpose2<<<g1, 256, 0, stream>>>(Whh, HH, 0, WhhT, 3 * HH, HH);
  int g2 = (HH * HH + 255) / 256;
  k_transpose2<<<g2, 256, 0, stream>>>(linA_w, HH, 0, linAT, HH, HH);
  k_transpose2<<<g2, 256, 0, stream>>>(fin_w, HH, 0, finT, HH, HH);
  k_transpose2<<<g2, 256, 0, stream>>>(linN_w, 2 * HH, 0, linN1T, HH, HH);
  k_embed<<<(NN * 64 + 255) / 256, 256, 0, stream>>>(nodeTypes, embN, x);
  k_count<<<(NE + 255) / 256, 256, 0, stream>>>(edst, deg, NE);
  k_count<<<(NN + 255) / 256, 256, 0, stream>>>(bs, bcnt, NN);
  k_scan<<<1, 1024, 0, stream>>>(deg, indptr, NN);
  k_scan<<<1, 1024, 0, stream>>>(bcnt, bptr, BB);
  k_copy_i<<<(NN + 255) / 256, 256, 0, stream>>>(indptr, cur, NN);
  k_copy_i<<<1, 256, 0, stream>>>(bptr, bcur, BB);
  k_scatter_e<<<(NE + 255) / 256, 256, 0, stream>>>(esrc, edst, erel, cur, esort);
  k_scatter_b<<<(NN + 255) / 256, 256, 0, stream>>>(bs, bcur, bnodes);

  // ---- 2 RGCN layers (shared weights), bf16 MFMA ----
  const unsigned int* xin = x;
  unsigned int* xout = x2;
  for (int layer = 0; layer < 2; ++layer) {
    for (int n0 = 0; n0 < NN; n0 += NCk) {
      int nc = NN - n0 < NCk ? NN - n0 : NCk;
      k_agg<<<(nc + 3) / 4, 256, 0, stream>>>(xin, indptr, esort, A, n0, nc);
      k_mgemm<1><<<(nc + 63) / 64, 256, 0, stream>>>(
          (const unsigned short*)A, KC, wcatT, KC, rgcnB,
          (void*)((unsigned short*)xout + (size_t)n0 * HH), nc, KC);
    }
    const unsigned int* t = xin;
    xin = xout;
    xout = (unsigned int*)t;
  }
  const unsigned short* nodeEmb = (const unsigned short*)xin;

  // ---- pooling + heads ----
  k_hG<<<BB, HH, 0, stream>>>(nodeEmb, bptr, bnodes, hG);
  k_action<<<BB, HH, 0, stream>>>(hG, linAT, linA_b, linAf_w, linAf_b, outA);
  k_final<<<BB, HH, 0, stream>>>(hG, finT, fin_b, finf_w, finf_b, outF);

  // ---- GRU input ----
  k_aggS<<<BB, 256, 0, stream>>>(seqin, nodeEmb, bptr, bnodes, aggS);
  k_ig<<<(BB * LL * HH + 255) / 256, 256, 0, stream>>>(aggS, embA, actin, ig);
  {
    dim3 g((3 * HH) / 64, (BB * LL) / 64);
    k_gemm<true, false><<<g, 256, 0, stream>>>(ig, HH, WihT, 3 * HH, bih, gi, 3 * HH,
                                               BB * LL, 3 * HH, HH);
  }
  k_gru<<<BB, HH, 0, stream>>>(gi, WhhT, bhh, hG, seq);

  // ---- node logits ----
  {
    dim3 g(HH / 64, (BB * LL) / 64);
    k_gemm<false, false><<<g, 256, 0, stream>>>(seq, HH, linN1T, HH, nullptr, part1, HH,
                                                BB * LL, HH, HH);
  }
  k_mgemm<0><<<(NN + 63) / 64, 256, 0, stream>>>(nodeEmb, HH, linN2bt, HH, nullptr,
                                                 (void*)part2, NN, HH);
  k_logits<<<NN / 4, 256, 0, stream>>>(part1, part2, linN_b, linNf_w, linNf_b, bs, logitsB);
  k_softmax<<<BB * LL, 64, 0, stream>>>(logitsB, bptr, bnodes, outNodes);
}

// Round 3
// 565.292 us; speedup vs baseline: 1.8171x; 1.1942x over previous
//
#include <hip/hip_runtime.h>
#include <math.h>

#define NN 12800
#define NE 204800
#define LL 24
#define HH 128
#define BB 64
#define RR 8
#define VAx 20
#define KC 1152  // R*H + H

typedef __attribute__((ext_vector_type(8))) short bf16x8;
typedef __attribute__((ext_vector_type(4))) float f32x4;

__device__ inline unsigned short f2bf(float f) {
  unsigned u = __float_as_uint(f);
  unsigned r = u + 0x7FFF + ((u >> 16) & 1);  // RNE
  return (unsigned short)(r >> 16);
}
__device__ inline float bf2f(unsigned short s) {
  return __uint_as_float(((unsigned)s) << 16);
}

// ---------------- small prep kernels ----------------

__global__ void k_transpose2(const float* __restrict__ W, int ld, int col0,
                             float* __restrict__ WT, int rows, int cols) {
  int idx = blockIdx.x * 256 + threadIdx.x;
  if (idx >= rows * cols) return;
  int r = idx / cols, c = idx - r * cols;
  WT[c * rows + r] = W[r * ld + col0 + c];
}

// WcatT[d][k] bf16 : k<1024 -> rgcnW[r=k>>7][h=k&127][d], else root[k-1024][d]
__global__ void k_prep_wcatT(const float* __restrict__ W, const float* __restrict__ root,
                             unsigned short* __restrict__ BT) {
  int idx = blockIdx.x * 256 + threadIdx.x;
  if (idx >= HH * KC) return;
  int d = idx / KC, k = idx - d * KC;
  float v = (k < 1024) ? W[(k >> 7) * (HH * HH) + (k & 127) * HH + d]
                       : root[(k - 1024) * HH + d];
  BT[idx] = f2bf(v);
}

// BT[d][k] bf16 = W[d*ld + col0 + k], 128x128
__global__ void k_prep_bt128(const float* __restrict__ W, int ld, int col0,
                             unsigned short* __restrict__ BT) {
  int idx = blockIdx.x * 256 + threadIdx.x;
  if (idx >= HH * HH) return;
  int d = idx >> 7, k = idx & 127;
  BT[idx] = f2bf(W[d * ld + col0 + k]);
}

// x (bf16 packed pairs) from embedding
__global__ void k_embed(const int* __restrict__ nt, const float* __restrict__ emb,
                        unsigned int* __restrict__ x) {
  int idx = blockIdx.x * 256 + threadIdx.x;
  if (idx >= NN * 64) return;
  int n = idx >> 6, p = idx & 63;
  const float* e = emb + (size_t)nt[n] * HH + p * 2;
  x[idx] = (unsigned)f2bf(e[0]) | ((unsigned)f2bf(e[1]) << 16);
}

__global__ void k_count(const int* __restrict__ key, int* __restrict__ cnt, int n) {
  int i = blockIdx.x * 256 + threadIdx.x;
  if (i < n) atomicAdd(&cnt[key[i]], 1);
}

// single-block exclusive scan; writes out[0..n] (out[n] = total)
__global__ void k_scan(const int* __restrict__ in, int* __restrict__ out, int n) {
  __shared__ int sh[1024];
  __shared__ int carry_s;
  if (threadIdx.x == 0) carry_s = 0;
  __syncthreads();
  for (int base = 0; base < n; base += 1024) {
    int i = base + threadIdx.x;
    int v = (i < n) ? in[i] : 0;
    sh[threadIdx.x] = v;
    __syncthreads();
    for (int off = 1; off < 1024; off <<= 1) {
      int t = (threadIdx.x >= off) ? sh[threadIdx.x - off] : 0;
      __syncthreads();
      sh[threadIdx.x] += t;
      __syncthreads();
    }
    int carry = carry_s;
    if (i < n) out[i] = carry + sh[threadIdx.x] - v;  // exclusive
    __syncthreads();
    if (threadIdx.x == 0) carry_s += sh[1023];
    __syncthreads();
  }
  if (threadIdx.x == 0) out[n] = carry_s;
}

__global__ void k_copy_i(const int* __restrict__ a, int* __restrict__ b, int n) {
  int i = blockIdx.x * 256 + threadIdx.x;
  if (i < n) b[i] = a[i];
}

__global__ void k_scatter_e(const int* __restrict__ src, const int* __restrict__ dst,
                            const int* __restrict__ rel, int* __restrict__ cur,
                            int* __restrict__ esort) {
  int e = blockIdx.x * 256 + threadIdx.x;
  if (e >= NE) return;
  int p = atomicAdd(&cur[dst[e]], 1);
  esort[p] = src[e] | (rel[e] << 16);
}

__global__ void k_scatter_b(const int* __restrict__ bs, int* __restrict__ cur,
                            int* __restrict__ bnodes) {
  int n = blockIdx.x * 256 + threadIdx.x;
  if (n >= NN) return;
  int p = atomicAdd(&cur[bs[n]], 1);
  bnodes[p] = n;
}

// ---------------- RGCN aggregation: one wave per node (bf16 x, bf16 A) ----------------
__global__ __launch_bounds__(256) void k_agg(const unsigned int* __restrict__ x,
                                             const int* __restrict__ indptr,
                                             const int* __restrict__ esort,
                                             unsigned int* __restrict__ A, int n0, int nc) {
  int wid = ((blockIdx.x * 256) + threadIdx.x) >> 6;
  int lane = threadIdx.x & 63;
  if (wid >= nc) return;
  int n = n0 + wid;
  float a0=0,a1=0,a2=0,a3=0,a4=0,a5=0,a6=0,a7=0;
  float b0=0,b1=0,b2=0,b3=0,b4=0,b5=0,b6=0,b7=0;
  int c0=0,c1=0,c2=0,c3=0,c4=0,c5=0,c6=0,c7=0;
  int e0 = indptr[n], e1 = indptr[n + 1];
  for (int e = e0; e < e1; ++e) {
    int pk = esort[e];
    int s = pk & 0xFFFF;
    int r = pk >> 16;
    unsigned v = x[s * 64 + lane];
    float v0 = bf2f((unsigned short)(v & 0xFFFF));
    float v1 = bf2f((unsigned short)(v >> 16));
    switch (r) {  // wave-uniform branch
      case 0: a0 += v0; b0 += v1; c0++; break;
      case 1: a1 += v0; b1 += v1; c1++; break;
      case 2: a2 += v0; b2 += v1; c2++; break;
      case 3: a3 += v0; b3 += v1; c3++; break;
      case 4: a4 += v0; b4 += v1; c4++; break;
      case 5: a5 += v0; b5 += v1; c5++; break;
      case 6: a6 += v0; b6 += v1; c6++; break;
      default: a7 += v0; b7 += v1; c7++; break;
    }
  }
  unsigned int* Ar = A + (size_t)wid * (KC / 2);
  float i0 = 1.0f / (float)(c0 > 0 ? c0 : 1);
  float i1 = 1.0f / (float)(c1 > 0 ? c1 : 1);
  float i2 = 1.0f / (float)(c2 > 0 ? c2 : 1);
  float i3 = 1.0f / (float)(c3 > 0 ? c3 : 1);
  float i4 = 1.0f / (float)(c4 > 0 ? c4 : 1);
  float i5 = 1.0f / (float)(c5 > 0 ? c5 : 1);
  float i6 = 1.0f / (float)(c6 > 0 ? c6 : 1);
  float i7 = 1.0f / (float)(c7 > 0 ? c7 : 1);
#define PACK(lo, hi) ((unsigned)f2bf(lo) | ((unsigned)f2bf(hi) << 16))
  Ar[0 * 64 + lane] = PACK(a0 * i0, b0 * i0);
  Ar[1 * 64 + lane] = PACK(a1 * i1, b1 * i1);
  Ar[2 * 64 + lane] = PACK(a2 * i2, b2 * i2);
  Ar[3 * 64 + lane] = PACK(a3 * i3, b3 * i3);
  Ar[4 * 64 + lane] = PACK(a4 * i4, b4 * i4);
  Ar[5 * 64 + lane] = PACK(a5 * i5, b5 * i5);
  Ar[6 * 64 + lane] = PACK(a6 * i6, b6 * i6);
  Ar[7 * 64 + lane] = PACK(a7 * i7, b7 * i7);
#undef PACK
  Ar[512 + lane] = x[n * 64 + lane];  // root term
}

// ---------------- bf16 MFMA GEMM: C[M,128] = A[M,K](bf16) * B[K,128] ----------------
template <int OUTMODE>
__global__ __launch_bounds__(256) void k_mgemm(const unsigned short* __restrict__ Abf, int lda,
                                               const unsigned short* __restrict__ BTbf, int ldb,
                                               const float* __restrict__ bias,
                                               void* __restrict__ C, int M, int K) {
  __shared__ unsigned int ldsu[(8192 + 16384) / 4];
  char* ldsc = (char*)ldsu;
  int tid = threadIdx.x;
  int m0 = blockIdx.x * 64;
  int w = tid >> 6, l = tid & 63;
  int lrow = l & 15, lg = l >> 4;
  f32x4 acc[8] = {};

  const char* Ab = (const char*)Abf;
  const char* Bb = (const char*)BTbf;
  int KT = K >> 6;
  for (int kt = 0; kt < KT; ++kt) {
    int k0 = kt << 6;
#pragma unroll
    for (int i = 0; i < 2; ++i) {
      int slot = i * 256 + tid;
      int row = slot >> 3;
      int colb = (slot & 7) << 4;
      int gr = m0 + row;
      gr = gr < M ? gr : M - 1;
      size_t srcb = ((size_t)gr * lda + k0) * 2 + (size_t)(colb ^ ((row & 7) << 4));
      __builtin_amdgcn_global_load_lds((const unsigned int*)(Ab + srcb),
                                       (unsigned int*)(ldsc + slot * 16), 16, 0, 0);
    }
#pragma unroll
    for (int i = 0; i < 4; ++i) {
      int slot = i * 256 + tid;
      int row = slot >> 3;
      int colb = (slot & 7) << 4;
      size_t srcb = ((size_t)row * ldb + k0) * 2 + (size_t)(colb ^ ((row & 7) << 4));
      __builtin_amdgcn_global_load_lds((const unsigned int*)(Bb + srcb),
                                       (unsigned int*)(ldsc + 8192 + slot * 16), 16, 0, 0);
    }
    __syncthreads();
#pragma unroll
    for (int h = 0; h < 2; ++h) {
      int arow = w * 16 + lrow;
      bf16x8 af = *(const bf16x8*)(ldsc + arow * 128 +
                                   ((h * 64 + lg * 16) ^ ((arow & 7) << 4)));
#pragma unroll
      for (int c = 0; c < 8; ++c) {
        int brow = c * 16 + lrow;
        bf16x8 bf = *(const bf16x8*)(ldsc + 8192 + brow * 128 +
                                     ((h * 64 + lg * 16) ^ ((brow & 7) << 4)));
        acc[c] = __builtin_amdgcn_mfma_f32_16x16x32_bf16(af, bf, acc[c], 0, 0, 0);
      }
    }
    __syncthreads();
  }
#pragma unroll
  for (int c = 0; c < 8; ++c) {
#pragma unroll
    for (int r = 0; r < 4; ++r) {
      int gm = m0 + w * 16 + lg * 4 + r;
      if (gm >= M) continue;
      int gn = c * 16 + lrow;
      float v = acc[c][r];
      if (OUTMODE == 1) {
        v = fmaxf(v + bias[gn], 0.f);
        ((unsigned short*)C)[(size_t)gm * HH + gn] = f2bf(v);
      } else {
        ((float*)C)[(size_t)gm * HH + gn] = v;
      }
    }
  }
}

// ---------------- generic fp32 tiled GEMM (kept for small GEMMs) ----------------
template <bool BIAS, bool RELU>
__global__ __launch_bounds__(256) void k_gemm(const float* __restrict__ Am, int lda,
                                              const float* __restrict__ Bm, int ldb,
                                              const float* __restrict__ bias,
                                              float* __restrict__ C, int ldc,
                                              int M, int Nc, int K) {
  __shared__ float As[16][65];
  __shared__ float Bs[16][65];
  int m0 = blockIdx.y * 64, n0 = blockIdx.x * 64;
  int tx = threadIdx.x & 15, ty = threadIdx.x >> 4;
  float acc[4][4] = {};
  for (int k0 = 0; k0 < K; k0 += 16) {
#pragma unroll
    for (int i = 0; i < 4; ++i) {
      int idx = threadIdx.x + i * 256;
      int kk = idx & 15, mm = idx >> 4;
      int gm = m0 + mm, gk = k0 + kk;
      As[kk][mm] = (gm < M && gk < K) ? Am[(size_t)gm * lda + gk] : 0.f;
    }
#pragma unroll
    for (int i = 0; i < 4; ++i) {
      int idx = threadIdx.x + i * 256;
      int nn = idx & 63, kk = idx >> 6;
      int gk = k0 + kk, gn = n0 + nn;
      Bs[kk][nn] = (gk < K && gn < Nc) ? Bm[(size_t)gk * ldb + gn] : 0.f;
    }
    __syncthreads();
#pragma unroll
    for (int kk = 0; kk < 16; ++kk) {
      float a[4], b[4];
#pragma unroll
      for (int i = 0; i < 4; ++i) a[i] = As[kk][ty * 4 + i];
#pragma unroll
      for (int j = 0; j < 4; ++j) b[j] = Bs[kk][tx * 4 + j];
#pragma unroll
      for (int i = 0; i < 4; ++i)
#pragma unroll
        for (int j = 0; j < 4; ++j) acc[i][j] = fmaf(a[i], b[j], acc[i][j]);
    }
    __syncthreads();
  }
#pragma unroll
  for (int i = 0; i < 4; ++i) {
    int gm = m0 + ty * 4 + i;
    if (gm >= M) continue;
#pragma unroll
    for (int j = 0; j < 4; ++j) {
      int gn = n0 + tx * 4 + j;
      if (gn >= Nc) continue;
      float v = acc[i][j];
      if (BIAS) v += bias[gn];
      if (RELU) v = fmaxf(v, 0.f);
      C[(size_t)gm * ldc + gn] = v;
    }
  }
}

// ---------------- graph mean pooling (bf16 in, fp32 out) ----------------
__global__ __launch_bounds__(128) void k_hG(const unsigned short* __restrict__ x,
                                            const int* __restrict__ bptr,
                                            const int* __restrict__ bnodes,
                                            float* __restrict__ hG) {
  int b = blockIdx.x, t = threadIdx.x;
  int i0 = bptr[b], i1 = bptr[b + 1];
  float s = 0.f;
  for (int i = i0; i < i1; ++i) s += bf2f(x[bnodes[i] * HH + t]);
  hG[b * HH + t] = s / (float)(i1 - i0);
}

// ---------------- heads ----------------
__global__ __launch_bounds__(128) void k_action(const float* __restrict__ hG,
                                                const float* __restrict__ linAT,
                                                const float* __restrict__ linA_b,
                                                const float* __restrict__ linAf_w,
                                                const float* __restrict__ linAf_b,
                                                float* __restrict__ outA) {
  int b = blockIdx.x, j = threadIdx.x;
  __shared__ float hsh[HH], t1[HH];
  hsh[j] = hG[b * HH + j];
  __syncthreads();
  float s = linA_b[j];
  for (int k = 0; k < HH; ++k) s = fmaf(hsh[k], linAT[k * HH + j], s);
  t1[j] = fmaxf(s, 0.f);
  __syncthreads();
  if (j < VAx) {
    float o = linAf_b[j];
    for (int k = 0; k < HH; ++k) o = fmaf(t1[k], linAf_w[j * HH + k], o);
    outA[b * VAx + j] = o;
  }
}

__global__ __launch_bounds__(128) void k_final(const float* __restrict__ hG,
                                               const float* __restrict__ finT,
                                               const float* __restrict__ fin_b,
                                               const float* __restrict__ finf_w,
                                               const float* __restrict__ finf_b,
                                               float* __restrict__ outF) {
  int b = blockIdx.x, j = threadIdx.x;
  __shared__ float hsh[HH], t1[HH];
  hsh[j] = hG[b * HH + j];
  __syncthreads();
  float s = fin_b[j];
  for (int k = 0; k < HH; ++k) s = fmaf(hsh[k], finT[k * HH + j], s);
  t1[j] = fmaxf(s, 0.f);
  __syncthreads();
  if (j == 0) {
    float o = finf_b[0];
    for (int k = 0; k < HH; ++k) o = fmaf(t1[k], finf_w[k], o);
    outF[b] = 1.f / (1.f + expf(-o));
  }
}

// ---------------- agg[b,l,h] = sum_{n in b} seq_in[n,l] * emb[n,h] (bf16 emb) ----------------
__global__ __launch_bounds__(256) void k_aggS(const float* __restrict__ seqin,
                                              const unsigned short* __restrict__ x,
                                              const int* __restrict__ bptr,
                                              const int* __restrict__ bnodes,
                                              float* __restrict__ aggS) {
  int b = blockIdx.x;
  int h = threadIdx.x & 127, l0 = threadIdx.x >> 7;
  float acc[12] = {};
  int i0 = bptr[b], i1 = bptr[b + 1];
  for (int i = i0; i < i1; ++i) {
    int n = bnodes[i];
    float e = bf2f(x[n * HH + h]);
#pragma unroll
    for (int t = 0; t < 12; ++t) {
      float s = seqin[n * LL + l0 + 2 * t];
      acc[t] = fmaf(s, e, acc[t]);
    }
  }
#pragma unroll
  for (int t = 0; t < 12; ++t) aggS[((size_t)b * LL + l0 + 2 * t) * HH + h] = acc[t];
}

__global__ void k_ig(const float* __restrict__ aggS, const float* __restrict__ embA,
                     const int* __restrict__ act, float* __restrict__ ig) {
  int idx = blockIdx.x * 256 + threadIdx.x;
  if (idx >= BB * LL * HH) return;
  int h = idx & 127;
  int bt = idx >> 7;
  int t = bt % LL, b = bt / LL;
  ig[idx] = (t == 0) ? embA[act[b] * HH + h] : aggS[((size_t)b * LL + (t - 1)) * HH + h];
}

// ---------------- GRU: 64 blocks x 384 threads, Whh column in registers ----------------
// thread tid = gate*128 + j; gate 0=r, 1=z, 2=n. Whh column [128] lives in VGPRs
// (static-indexed full unroll). h[128] in LDS; 2 barriers per step.
__global__ __launch_bounds__(384) void k_gru(const float* __restrict__ gi,
                                             const float* __restrict__ WhhT,  // [128][384]
                                             const float* __restrict__ bhh,
                                             const float* __restrict__ hG,
                                             float* __restrict__ seqout) {
  int b = blockIdx.x, tid = threadIdx.x;
  int gate = tid >> 7, j = tid & 127;
  __shared__ float h[HH];
  __shared__ float sz[HH], sg[HH];
  float w[HH];
#pragma unroll
  for (int k = 0; k < HH; ++k) w[k] = WhhT[k * 384 + tid];
  float bh = bhh[tid];
  if (tid < HH) h[tid] = hG[b * HH + tid];
  __syncthreads();
  const float* gib = gi + (size_t)b * LL * 384;
  for (int t = 0; t < LL; ++t) {
    float giv = gib[t * 384 + tid];
    float gin = (gate == 0) ? gib[t * 384 + 256 + j] : 0.f;  // wave-uniform branch
    float hj = h[j];
    float g0 = 0.f, g1 = 0.f, g2 = 0.f, g3 = 0.f;
    const float4* h4 = (const float4*)h;
#pragma unroll
    for (int k4 = 0; k4 < HH / 4; ++k4) {
      float4 hv = h4[k4];
      g0 = fmaf(w[4 * k4 + 0], hv.x, g0);
      g1 = fmaf(w[4 * k4 + 1], hv.y, g1);
      g2 = fmaf(w[4 * k4 + 2], hv.z, g2);
      g3 = fmaf(w[4 * k4 + 3], hv.w, g3);
    }
    float g = bh + ((g0 + g1) + (g2 + g3));
    float r = 0.f;
    if (gate == 0) {
      r = 1.f / (1.f + expf(-(giv + g)));
    } else if (gate == 1) {
      sz[j] = 1.f / (1.f + expf(-(giv + g)));
    } else {
      sg[j] = g;  // raw gh_n (bhh_n already in g); i_n added below
    }
    __syncthreads();
    if (gate == 0) {
      float n = tanhf(gin + r * sg[j]);
      float z = sz[j];
      float hn = (1.f - z) * n + z * hj;
      h[j] = hn;
      seqout[((size_t)b * LL + t) * HH + j] = hn;
    }
    __syncthreads();
  }
}

// ---------------- fused logits ----------------
__global__ __launch_bounds__(256) void k_logits(const float* __restrict__ part1,
                                                const float* __restrict__ part2,
                                                const float* __restrict__ linN_b,
                                                const float* __restrict__ linNf_w,
                                                const float* __restrict__ linNf_b,
                                                const int* __restrict__ bs,
                                                float* __restrict__ logits) {
  int wid = ((blockIdx.x * 256) + threadIdx.x) >> 6;
  int lane = threadIdx.x & 63;
  if (wid >= NN) return;
  int n = wid;
  int b = bs[n];
  float p2a = part2[n * HH + lane] + linN_b[lane];
  float p2b = part2[n * HH + 64 + lane] + linN_b[64 + lane];
  float wa = linNf_w[lane], wb = linNf_w[64 + lane];
  const float* p1 = part1 + (size_t)b * LL * HH;
  float bf = linNf_b[0];
  for (int l = 0; l < LL; ++l) {
    float v = fmaxf(p1[l * HH + lane] + p2a, 0.f) * wa +
              fmaxf(p1[l * HH + 64 + lane] + p2b, 0.f) * wb;
#pragma unroll
    for (int off = 32; off > 0; off >>= 1) v += __shfl_down(v, off);
    if (lane == 0) logits[n * LL + l] = v + bf;
  }
}

// ---------------- segment softmax ----------------
__global__ __launch_bounds__(64) void k_softmax(const float* __restrict__ logits,
                                                const int* __restrict__ bptr,
                                                const int* __restrict__ bnodes,
                                                float* __restrict__ outN) {
  int b = blockIdx.x / LL, l = blockIdx.x % LL;
  int lane = threadIdx.x;
  int i0 = bptr[b], i1 = bptr[b + 1];
  float m = -1e30f;
  for (int i = i0 + lane; i < i1; i += 64) m = fmaxf(m, logits[bnodes[i] * LL + l]);
#pragma unroll
  for (int off = 32; off > 0; off >>= 1) m = fmaxf(m, __shfl_xor(m, off));
  float s = 0.f;
  for (int i = i0 + lane; i < i1; i += 64) s += expf(logits[bnodes[i] * LL + l] - m);
#pragma unroll
  for (int off = 32; off > 0; off >>= 1) s += __shfl_xor(s, off);
  float inv = 1.f / s;
  for (int i = i0 + lane; i < i1; i += 64) {
    int n = bnodes[i];
    outN[n * LL + l] = expf(logits[n * LL + l] - m) * inv;
  }
}

// ---------------- host ----------------
extern "C" void kernel_launch(void* const* d_in, const int* in_sizes, int n_in,
                              void* d_out, int out_size, void* d_ws, size_t ws_size,
                              hipStream_t stream) {
  const int* nodeTypes = (const int*)d_in[0];
  const int* esrc = (const int*)d_in[1];
  const int* edst = esrc + NE;
  const int* erel = (const int*)d_in[2];
  const int* bs = (const int*)d_in[3];
  const float* seqin = (const float*)d_in[4];
  const int* actin = (const int*)d_in[7];
  const float* embN = (const float*)d_in[8];
  const float* embA = (const float*)d_in[9];
  const float* rgcnW = (const float*)d_in[10];
  const float* rgcnRoot = (const float*)d_in[11];
  const float* rgcnB = (const float*)d_in[12];
  const float* Wih = (const float*)d_in[13];
  const float* Whh = (const float*)d_in[14];
  const float* bih = (const float*)d_in[15];
  const float* bhh = (const float*)d_in[16];
  const float* linA_w = (const float*)d_in[17];
  const float* linA_b = (const float*)d_in[18];
  const float* linAf_w = (const float*)d_in[19];
  const float* linAf_b = (const float*)d_in[20];
  const float* linN_w = (const float*)d_in[21];
  const float* linN_b = (const float*)d_in[22];
  const float* linNf_w = (const float*)d_in[23];
  const float* linNf_b = (const float*)d_in[24];
  const float* fin_w = (const float*)d_in[25];
  const float* fin_b = (const float*)d_in[26];
  const float* finf_w = (const float*)d_in[27];
  const float* finf_b = (const float*)d_in[28];

  float* outA = (float*)d_out;
  float* outNodes = outA + BB * VAx;
  float* outF = outNodes + (size_t)NN * LL;

  char* basep = (char*)d_ws;
  size_t off = 0;
  auto alloc = [&](size_t bytes) -> void* {
    void* p = basep + off;
    off = (off + bytes + 255) & ~(size_t)255;
    return p;
  };

  unsigned int* x = (unsigned int*)alloc(sizeof(unsigned int) * NN * 64);   // bf16 pairs
  unsigned int* x2 = (unsigned int*)alloc(sizeof(unsigned int) * NN * 64);  // bf16 pairs
  float* hG = (float*)alloc(sizeof(float) * BB * HH);
  unsigned short* wcatT = (unsigned short*)alloc(sizeof(unsigned short) * HH * KC);
  unsigned short* linN2bt = (unsigned short*)alloc(sizeof(unsigned short) * HH * HH);
  float* WihT = (float*)alloc(sizeof(float) * HH * 3 * HH);
  float* WhhT = (float*)alloc(sizeof(float) * HH * 3 * HH);
  float* linAT = (float*)alloc(sizeof(float) * HH * HH);
  float* finT = (float*)alloc(sizeof(float) * HH * HH);
  float* linN1T = (float*)alloc(sizeof(float) * HH * HH);
  float* aggS = (float*)alloc(sizeof(float) * BB * LL * HH);
  float* ig = (float*)alloc(sizeof(float) * BB * LL * HH);
  float* gi = (float*)alloc(sizeof(float) * BB * LL * 3 * HH);
  float* seq = (float*)alloc(sizeof(float) * BB * LL * HH);
  float* part1 = (float*)alloc(sizeof(float) * BB * LL * HH);
  float* part2 = (float*)alloc(sizeof(float) * NN * HH);
  float* logitsB = (float*)alloc(sizeof(float) * NN * LL);
  int* deg = (int*)alloc(sizeof(int) * NN);
  int* indptr = (int*)alloc(sizeof(int) * (NN + 1));
  int* cur = (int*)alloc(sizeof(int) * NN);
  int* esort = (int*)alloc(sizeof(int) * NE);
  int* bcnt = (int*)alloc(sizeof(int) * BB);
  int* bptr = (int*)alloc(sizeof(int) * (BB + 1));
  int* bcur = (int*)alloc(sizeof(int) * BB);
  int* bnodes = (int*)alloc(sizeof(int) * NN);

  size_t remain = (ws_size > off) ? (ws_size - off) : 0;
  int NCk = NN;
  while ((size_t)NCk * KC * 2 > remain && NCk > 100) NCk >>= 1;
  unsigned int* A = (unsigned int*)alloc((size_t)NCk * (KC / 2) * sizeof(unsigned int));

  // ---- prep ----
  hipMemsetAsync(deg, 0, sizeof(int) * NN, stream);
  hipMemsetAsync(bcnt, 0, sizeof(int) * BB, stream);
  k_prep_wcatT<<<(HH * KC + 255) / 256, 256, 0, stream>>>(rgcnW, rgcnRoot, wcatT);
  k_prep_bt128<<<(HH * HH + 255) / 256, 256, 0, stream>>>(linN_w, 2 * HH, HH, linN2bt);
  int g1 = (3 * HH * HH + 255) / 256;
  k_transpose2<<<g1, 256, 0, stream>>>(Wih, HH, 0, WihT, 3 * HH, HH);
  k_transpose2<<<g1, 256, 0, stream>>>(Whh, HH, 0, WhhT, 3 * HH, HH);
  int g2 = (HH * HH + 255) / 256;
  k_transpose2<<<g2, 256, 0, stream>>>(linA_w, HH, 0, linAT, HH, HH);
  k_transpose2<<<g2, 256, 0, stream>>>(fin_w, HH, 0, finT, HH, HH);
  k_transpose2<<<g2, 256, 0, stream>>>(linN_w, 2 * HH, 0, linN1T, HH, HH);
  k_embed<<<(NN * 64 + 255) / 256, 256, 0, stream>>>(nodeTypes, embN, x);
  k_count<<<(NE + 255) / 256, 256, 0, stream>>>(edst, deg, NE);
  k_count<<<(NN + 255) / 256, 256, 0, stream>>>(bs, bcnt, NN);
  k_scan<<<1, 1024, 0, stream>>>(deg, indptr, NN);
  k_scan<<<1, 1024, 0, stream>>>(bcnt, bptr, BB);
  k_copy_i<<<(NN + 255) / 256, 256, 0, stream>>>(indptr, cur, NN);
  k_copy_i<<<1, 256, 0, stream>>>(bptr, bcur, BB);
  k_scatter_e<<<(NE + 255) / 256, 256, 0, stream>>>(esrc, edst, erel, cur, esort);
  k_scatter_b<<<(NN + 255) / 256, 256, 0, stream>>>(bs, bcur, bnodes);

  // ---- 2 RGCN layers (shared weights), bf16 MFMA ----
  const unsigned int* xin = x;
  unsigned int* xout = x2;
  for (int layer = 0; layer < 2; ++layer) {
    for (int n0 = 0; n0 < NN; n0 += NCk) {
      int nc = NN - n0 < NCk ? NN - n0 : NCk;
      k_agg<<<(nc + 3) / 4, 256, 0, stream>>>(xin, indptr, esort, A, n0, nc);
      k_mgemm<1><<<(nc + 63) / 64, 256, 0, stream>>>(
          (const unsigned short*)A, KC, wcatT, KC, rgcnB,
          (void*)((unsigned short*)xout + (size_t)n0 * HH), nc, KC);
    }
    const unsigned int* t = xin;
    xin = xout;
    xout = (unsigned int*)t;
  }
  const unsigned short* nodeEmb = (const unsigned short*)xin;

  // ---- pooling + heads ----
  k_hG<<<BB, HH, 0, stream>>>(nodeEmb, bptr, bnodes, hG);
  k_action<<<BB, HH, 0, stream>>>(hG, linAT, linA_b, linAf_w, linAf_b, outA);
  k_final<<<BB, HH, 0, stream>>>(hG, finT, fin_b, finf_w, finf_b, outF);

  // ---- GRU input ----
  k_aggS<<<BB, 256, 0, stream>>>(seqin, nodeEmb, bptr, bnodes, aggS);
  k_ig<<<(BB * LL * HH + 255) / 256, 256, 0, stream>>>(aggS, embA, actin, ig);
  {
    dim3 g((3 * HH) / 64, (BB * LL) / 64);
    k_gemm<true, false><<<g, 256, 0, stream>>>(ig, HH, WihT, 3 * HH, bih, gi, 3 * HH,
                                               BB * LL, 3 * HH, HH);
  }
  k_gru<<<BB, 384, 0, stream>>>(gi, WhhT, bhh, hG, seq);

  // ---- node logits ----
  {
    dim3 g(HH / 64, (BB * LL) / 64);
    k_gemm<false, false><<<g, 256, 0, stream>>>(seq, HH, linN1T, HH, nullptr, part1, HH,
                                                BB * LL, HH, HH);
  }
  k_mgemm<0><<<(NN + 63) / 64, 256, 0, stream>>>(nodeEmb, HH, linN2bt, HH, nullptr,
                                                 (void*)part2, NN, HH);
  k_logits<<<NN / 4, 256, 0, stream>>>(part1, part2, linN_b, linNf_w, linNf_b, bs, logitsB);
  k_softmax<<<BB * LL, 64, 0, stream>>>(logitsB, bptr, bnodes, outNodes);
}

// Round 4
// 429.874 us; speedup vs baseline: 2.3895x; 1.3150x over previous
//
#include <hip/hip_runtime.h>
#include <math.h>

#define NN 12800
#define NE 204800
#define LL 24
#define HH 128
#define BB 64
#define RR 8
#define VAx 20
#define KC 1152  // R*H + H
#define CHK 8    // node chunks per batch for aggS

typedef __attribute__((ext_vector_type(8))) short bf16x8;
typedef __attribute__((ext_vector_type(4))) float f32x4;

__device__ inline unsigned short f2bf(float f) {
  unsigned u = __float_as_uint(f);
  unsigned r = u + 0x7FFF + ((u >> 16) & 1);  // RNE
  return (unsigned short)(r >> 16);
}
__device__ inline float bf2f(unsigned short s) {
  return __uint_as_float(((unsigned)s) << 16);
}

// ---------------- mega prep: all weight transforms + embed + zeroing, 1 launch ----------------
__global__ void k_prep(const float* __restrict__ rgcnW, const float* __restrict__ rgcnRoot,
                       unsigned short* __restrict__ wcatT,
                       const float* __restrict__ linN_w, unsigned short* __restrict__ linN2bt,
                       const float* __restrict__ Wih, float* __restrict__ WihT,
                       const float* __restrict__ Whh, float* __restrict__ WhhT,
                       const float* __restrict__ linA_w, float* __restrict__ linAT,
                       const float* __restrict__ fin_w, float* __restrict__ finT,
                       float* __restrict__ linN1T,
                       const int* __restrict__ nt, const float* __restrict__ embN,
                       unsigned int* __restrict__ x,
                       int* __restrict__ deg, int* __restrict__ bcnt) {
  int idx = blockIdx.x * 256 + threadIdx.x;
  if (idx < HH * KC) {  // wcatT[d][k]
    int d = idx / KC, k = idx - d * KC;
    float v = (k < 1024) ? rgcnW[(k >> 7) * (HH * HH) + (k & 127) * HH + d]
                         : rgcnRoot[(k - 1024) * HH + d];
    wcatT[idx] = f2bf(v);
    return;
  }
  idx -= HH * KC;
  if (idx < HH * HH) {  // linN2bt[d][k] = linN_w[d][128+k]
    int d = idx >> 7, k = idx & 127;
    linN2bt[idx] = f2bf(linN_w[d * 2 * HH + HH + k]);
    return;
  }
  idx -= HH * HH;
  if (idx < 3 * HH * HH) {  // WihT[c*384+r] = Wih[r*128+c]
    int r = idx / HH, c = idx - r * HH;
    WihT[c * 384 + r] = Wih[r * HH + c];
    return;
  }
  idx -= 3 * HH * HH;
  if (idx < 3 * HH * HH) {  // WhhT
    int r = idx / HH, c = idx - r * HH;
    WhhT[c * 384 + r] = Whh[r * HH + c];
    return;
  }
  idx -= 3 * HH * HH;
  if (idx < HH * HH) {  // linAT
    int r = idx >> 7, c = idx & 127;
    linAT[c * HH + r] = linA_w[r * HH + c];
    return;
  }
  idx -= HH * HH;
  if (idx < HH * HH) {  // finT
    int r = idx >> 7, c = idx & 127;
    finT[c * HH + r] = fin_w[r * HH + c];
    return;
  }
  idx -= HH * HH;
  if (idx < HH * HH) {  // linN1T[c*128+r] = linN_w[r][c]
    int r = idx >> 7, c = idx & 127;
    linN1T[c * HH + r] = linN_w[r * 2 * HH + c];
    return;
  }
  idx -= HH * HH;
  if (idx < NN * 64) {  // embed -> bf16 pairs
    int n = idx >> 6, p = idx & 63;
    const float* e = embN + (size_t)nt[n] * HH + p * 2;
    x[idx] = (unsigned)f2bf(e[0]) | ((unsigned)f2bf(e[1]) << 16);
    return;
  }
  idx -= NN * 64;
  if (idx < NN) { deg[idx] = 0; return; }
  idx -= NN;
  if (idx < BB) bcnt[idx] = 0;
}
#define PREP_TOTAL (HH * KC + HH * HH + 3 * HH * HH + 3 * HH * HH + HH * HH + HH * HH + HH * HH + NN * 64 + NN + BB)

__global__ void k_count2(const int* __restrict__ edst, int* __restrict__ deg,
                         const int* __restrict__ bs, int* __restrict__ bcnt) {
  int i = blockIdx.x * 256 + threadIdx.x;
  if (i < NE) atomicAdd(&deg[edst[i]], 1);
  if (i < NN) atomicAdd(&bcnt[bs[i]], 1);
}

// two scans in one launch: block0 = deg->indptr(+cur), block1 = bcnt->bptr(+bcur)
__global__ __launch_bounds__(1024) void k_scan2(const int* __restrict__ deg, int* __restrict__ indptr,
                                                int* __restrict__ cur,
                                                const int* __restrict__ bcnt, int* __restrict__ bptr,
                                                int* __restrict__ bcur) {
  const int* in;
  int *out, *out2;
  int n;
  if (blockIdx.x == 0) { in = deg; out = indptr; out2 = cur; n = NN; }
  else { in = bcnt; out = bptr; out2 = bcur; n = BB; }
  __shared__ int ws[16];
  int tid = threadIdx.x;
  int per = (n + 1023) >> 10;
  int i0 = tid * per;
  int s = 0;
  for (int k = 0; k < per; ++k) {
    int i = i0 + k;
    if (i < n) s += in[i];
  }
  int lane = tid & 63, wv = tid >> 6;
  int incl = s;
#pragma unroll
  for (int off = 1; off < 64; off <<= 1) {
    int t = __shfl_up(incl, off);
    if (lane >= off) incl += t;
  }
  if (lane == 63) ws[wv] = incl;
  __syncthreads();
  if (tid < 16) {
    int v = ws[tid];
    int inc = v;
#pragma unroll
    for (int off = 1; off < 16; off <<= 1) {
      int t = __shfl_up(inc, off);
      if (tid >= off) inc += t;
    }
    ws[tid] = inc - v;  // exclusive
  }
  __syncthreads();
  int run = ws[wv] + incl - s;  // exclusive prefix for this thread's first element
  for (int k = 0; k < per; ++k) {
    int i = i0 + k;
    if (i < n) {
      out[i] = run;
      out2[i] = run;
      run += in[i];
      if (i == n - 1) out[n] = run;
    }
  }
}

__global__ void k_scatter2(const int* __restrict__ esrc, const int* __restrict__ edst,
                           const int* __restrict__ erel, int* __restrict__ cur,
                           int* __restrict__ esort, const int* __restrict__ bs,
                           int* __restrict__ bcur, int* __restrict__ bnodes) {
  int i = blockIdx.x * 256 + threadIdx.x;
  if (i < NE) {
    int p = atomicAdd(&cur[edst[i]], 1);
    esort[p] = esrc[i] | (erel[i] << 16);
  }
  if (i < NN) {
    int p = atomicAdd(&bcur[bs[i]], 1);
    bnodes[p] = i;
  }
}

// ---------------- RGCN aggregation: one wave per node (bf16 x, bf16 A) ----------------
__global__ __launch_bounds__(256) void k_agg(const unsigned int* __restrict__ x,
                                             const int* __restrict__ indptr,
                                             const int* __restrict__ esort,
                                             unsigned int* __restrict__ A, int n0, int nc) {
  int wid = ((blockIdx.x * 256) + threadIdx.x) >> 6;
  int lane = threadIdx.x & 63;
  if (wid >= nc) return;
  int n = n0 + wid;
  float a0=0,a1=0,a2=0,a3=0,a4=0,a5=0,a6=0,a7=0;
  float b0=0,b1=0,b2=0,b3=0,b4=0,b5=0,b6=0,b7=0;
  int c0=0,c1=0,c2=0,c3=0,c4=0,c5=0,c6=0,c7=0;
  int e0 = indptr[n], e1 = indptr[n + 1];
  for (int e = e0; e < e1; ++e) {
    int pk = esort[e];
    int s = pk & 0xFFFF;
    int r = pk >> 16;
    unsigned v = x[s * 64 + lane];
    float v0 = bf2f((unsigned short)(v & 0xFFFF));
    float v1 = bf2f((unsigned short)(v >> 16));
    switch (r) {  // wave-uniform branch
      case 0: a0 += v0; b0 += v1; c0++; break;
      case 1: a1 += v0; b1 += v1; c1++; break;
      case 2: a2 += v0; b2 += v1; c2++; break;
      case 3: a3 += v0; b3 += v1; c3++; break;
      case 4: a4 += v0; b4 += v1; c4++; break;
      case 5: a5 += v0; b5 += v1; c5++; break;
      case 6: a6 += v0; b6 += v1; c6++; break;
      default: a7 += v0; b7 += v1; c7++; break;
    }
  }
  unsigned int* Ar = A + (size_t)wid * (KC / 2);
  float i0 = 1.0f / (float)(c0 > 0 ? c0 : 1);
  float i1 = 1.0f / (float)(c1 > 0 ? c1 : 1);
  float i2 = 1.0f / (float)(c2 > 0 ? c2 : 1);
  float i3 = 1.0f / (float)(c3 > 0 ? c3 : 1);
  float i4 = 1.0f / (float)(c4 > 0 ? c4 : 1);
  float i5 = 1.0f / (float)(c5 > 0 ? c5 : 1);
  float i6 = 1.0f / (float)(c6 > 0 ? c6 : 1);
  float i7 = 1.0f / (float)(c7 > 0 ? c7 : 1);
#define PACK(lo, hi) ((unsigned)f2bf(lo) | ((unsigned)f2bf(hi) << 16))
  Ar[0 * 64 + lane] = PACK(a0 * i0, b0 * i0);
  Ar[1 * 64 + lane] = PACK(a1 * i1, b1 * i1);
  Ar[2 * 64 + lane] = PACK(a2 * i2, b2 * i2);
  Ar[3 * 64 + lane] = PACK(a3 * i3, b3 * i3);
  Ar[4 * 64 + lane] = PACK(a4 * i4, b4 * i4);
  Ar[5 * 64 + lane] = PACK(a5 * i5, b5 * i5);
  Ar[6 * 64 + lane] = PACK(a6 * i6, b6 * i6);
  Ar[7 * 64 + lane] = PACK(a7 * i7, b7 * i7);
#undef PACK
  Ar[512 + lane] = x[n * 64 + lane];  // root term
}

// ---------------- bf16 MFMA GEMM: C[M,128] = A[M,K](bf16) * B[K,128] ----------------
template <int OUTMODE>
__global__ __launch_bounds__(256) void k_mgemm(const unsigned short* __restrict__ Abf, int lda,
                                               const unsigned short* __restrict__ BTbf, int ldb,
                                               const float* __restrict__ bias,
                                               void* __restrict__ C, int M, int K) {
  __shared__ unsigned int ldsu[(8192 + 16384) / 4];
  char* ldsc = (char*)ldsu;
  int tid = threadIdx.x;
  int m0 = blockIdx.x * 64;
  int w = tid >> 6, l = tid & 63;
  int lrow = l & 15, lg = l >> 4;
  f32x4 acc[8] = {};

  const char* Ab = (const char*)Abf;
  const char* Bb = (const char*)BTbf;
  int KT = K >> 6;
  for (int kt = 0; kt < KT; ++kt) {
    int k0 = kt << 6;
#pragma unroll
    for (int i = 0; i < 2; ++i) {
      int slot = i * 256 + tid;
      int row = slot >> 3;
      int colb = (slot & 7) << 4;
      int gr = m0 + row;
      gr = gr < M ? gr : M - 1;
      size_t srcb = ((size_t)gr * lda + k0) * 2 + (size_t)(colb ^ ((row & 7) << 4));
      __builtin_amdgcn_global_load_lds((const unsigned int*)(Ab + srcb),
                                       (unsigned int*)(ldsc + slot * 16), 16, 0, 0);
    }
#pragma unroll
    for (int i = 0; i < 4; ++i) {
      int slot = i * 256 + tid;
      int row = slot >> 3;
      int colb = (slot & 7) << 4;
      size_t srcb = ((size_t)row * ldb + k0) * 2 + (size_t)(colb ^ ((row & 7) << 4));
      __builtin_amdgcn_global_load_lds((const unsigned int*)(Bb + srcb),
                                       (unsigned int*)(ldsc + 8192 + slot * 16), 16, 0, 0);
    }
    __syncthreads();
#pragma unroll
    for (int h = 0; h < 2; ++h) {
      int arow = w * 16 + lrow;
      bf16x8 af = *(const bf16x8*)(ldsc + arow * 128 +
                                   ((h * 64 + lg * 16) ^ ((arow & 7) << 4)));
#pragma unroll
      for (int c = 0; c < 8; ++c) {
        int brow = c * 16 + lrow;
        bf16x8 bf = *(const bf16x8*)(ldsc + 8192 + brow * 128 +
                                     ((h * 64 + lg * 16) ^ ((brow & 7) << 4)));
        acc[c] = __builtin_amdgcn_mfma_f32_16x16x32_bf16(af, bf, acc[c], 0, 0, 0);
      }
    }
    __syncthreads();
  }
#pragma unroll
  for (int c = 0; c < 8; ++c) {
#pragma unroll
    for (int r = 0; r < 4; ++r) {
      int gm = m0 + w * 16 + lg * 4 + r;
      if (gm >= M) continue;
      int gn = c * 16 + lrow;
      float v = acc[c][r];
      if (OUTMODE == 1) {
        v = fmaxf(v + bias[gn], 0.f);
        ((unsigned short*)C)[(size_t)gm * HH + gn] = f2bf(v);
      } else {
        ((float*)C)[(size_t)gm * HH + gn] = v;
      }
    }
  }
}

// ---------------- generic fp32 tiled GEMM (small GEMMs) ----------------
template <bool BIAS, bool RELU>
__global__ __launch_bounds__(256) void k_gemm(const float* __restrict__ Am, int lda,
                                              const float* __restrict__ Bm, int ldb,
                                              const float* __restrict__ bias,
                                              float* __restrict__ C, int ldc,
                                              int M, int Nc, int K) {
  __shared__ float As[16][65];
  __shared__ float Bs[16][65];
  int m0 = blockIdx.y * 64, n0 = blockIdx.x * 64;
  int tx = threadIdx.x & 15, ty = threadIdx.x >> 4;
  float acc[4][4] = {};
  for (int k0 = 0; k0 < K; k0 += 16) {
#pragma unroll
    for (int i = 0; i < 4; ++i) {
      int idx = threadIdx.x + i * 256;
      int kk = idx & 15, mm = idx >> 4;
      int gm = m0 + mm, gk = k0 + kk;
      As[kk][mm] = (gm < M && gk < K) ? Am[(size_t)gm * lda + gk] : 0.f;
    }
#pragma unroll
    for (int i = 0; i < 4; ++i) {
      int idx = threadIdx.x + i * 256;
      int nn = idx & 63, kk = idx >> 6;
      int gk = k0 + kk, gn = n0 + nn;
      Bs[kk][nn] = (gk < K && gn < Nc) ? Bm[(size_t)gk * ldb + gn] : 0.f;
    }
    __syncthreads();
#pragma unroll
    for (int kk = 0; kk < 16; ++kk) {
      float a[4], b[4];
#pragma unroll
      for (int i = 0; i < 4; ++i) a[i] = As[kk][ty * 4 + i];
#pragma unroll
      for (int j = 0; j < 4; ++j) b[j] = Bs[kk][tx * 4 + j];
#pragma unroll
      for (int i = 0; i < 4; ++i)
#pragma unroll
        for (int j = 0; j < 4; ++j) acc[i][j] = fmaf(a[i], b[j], acc[i][j]);
    }
    __syncthreads();
  }
#pragma unroll
  for (int i = 0; i < 4; ++i) {
    int gm = m0 + ty * 4 + i;
    if (gm >= M) continue;
#pragma unroll
    for (int j = 0; j < 4; ++j) {
      int gn = n0 + tx * 4 + j;
      if (gn >= Nc) continue;
      float v = acc[i][j];
      if (BIAS) v += bias[gn];
      if (RELU) v = fmaxf(v, 0.f);
      C[(size_t)gm * ldc + gn] = v;
    }
  }
}

// ---------------- aggS partials: 512 blocks (64 batches x 8 chunks) ----------------
// part[bc][l][h], l=0..23 weighted sums, l=24 = plain emb sum (for hG)
__global__ __launch_bounds__(256) void k_aggS_part(const float* __restrict__ seqin,
                                                   const unsigned short* __restrict__ x,
                                                   const int* __restrict__ bptr,
                                                   const int* __restrict__ bnodes,
                                                   float* __restrict__ part) {
  int bc = blockIdx.x, b = bc >> 3, c = bc & 7;
  int h = threadIdx.x & 127, l0 = threadIdx.x >> 7;  // l0 in {0,1}
  int i0 = bptr[b], i1 = bptr[b + 1];
  int len = i1 - i0;
  int per = (len + CHK - 1) / CHK;
  int j0 = i0 + c * per;
  int j1 = j0 + per;
  if (j1 > i1) j1 = i1;
  float acc[12] = {};
  float esum = 0.f;
  for (int i = j0; i < j1; ++i) {
    int n = bnodes[i];
    float e = bf2f(x[n * HH + h]);
    esum += e;
    const float* srow = seqin + (size_t)n * LL;
#pragma unroll
    for (int t = 0; t < 12; ++t) acc[t] = fmaf(srow[l0 + 2 * t], e, acc[t]);
  }
  float* p = part + (size_t)bc * 25 * HH + h;
#pragma unroll
  for (int t = 0; t < 12; ++t) p[(l0 + 2 * t) * HH] = acc[t];
  if (l0 == 0) p[24 * HH] = esum;
}

// reduce partials; writes ig (with SOS at t=0) and hG
__global__ void k_aggS_red(const float* __restrict__ part, const int* __restrict__ bptr,
                           const float* __restrict__ embA, const int* __restrict__ act,
                           float* __restrict__ ig, float* __restrict__ hG) {
  int idx = blockIdx.x * 256 + threadIdx.x;
  if (idx >= BB * 25 * HH) return;
  int h = idx & 127;
  int rem = idx >> 7;
  int l = rem % 25, b = rem / 25;
  if (l == 23) {  // agg[23] is dropped by [:, :L]; reuse slot to fill ig[b][0] = SOS
    ig[((size_t)b * LL) * HH + h] = embA[(size_t)act[b] * HH + h];
    return;
  }
  float s = 0.f;
#pragma unroll
  for (int c = 0; c < CHK; ++c) s += part[(((size_t)(b * CHK + c)) * 25 + l) * HH + h];
  if (l == 24) {
    int len = bptr[b + 1] - bptr[b];
    hG[b * HH + h] = s / (float)len;
  } else {
    ig[((size_t)b * LL + l + 1) * HH + h] = s;
  }
}

// ---------------- merged heads: 128 blocks (b = bid>>1, which = bid&1) ----------------
__global__ __launch_bounds__(128) void k_heads(const float* __restrict__ hG,
                                               const float* __restrict__ linAT,
                                               const float* __restrict__ linA_b,
                                               const float* __restrict__ linAf_w,
                                               const float* __restrict__ linAf_b,
                                               const float* __restrict__ finT,
                                               const float* __restrict__ fin_b,
                                               const float* __restrict__ finf_w,
                                               const float* __restrict__ finf_b,
                                               float* __restrict__ outA,
                                               float* __restrict__ outF) {
  int b = blockIdx.x >> 1, which = blockIdx.x & 1, j = threadIdx.x;
  __shared__ float hsh[HH], t1[HH];
  hsh[j] = hG[b * HH + j];
  __syncthreads();
  const float* Wt = which ? finT : linAT;
  const float* bb = which ? fin_b : linA_b;
  float s = bb[j];
  for (int k = 0; k < HH; ++k) s = fmaf(hsh[k], Wt[k * HH + j], s);
  t1[j] = fmaxf(s, 0.f);
  __syncthreads();
  if (which == 0) {
    if (j < VAx) {
      float o = linAf_b[j];
      for (int k = 0; k < HH; ++k) o = fmaf(t1[k], linAf_w[j * HH + k], o);
      outA[b * VAx + j] = o;
    }
  } else if (j == 0) {
    float o = finf_b[0];
    for (int k = 0; k < HH; ++k) o = fmaf(t1[k], finf_w[k], o);
    outF[b] = 1.f / (1.f + expf(-o));
  }
}

// ---------------- GRU: 64 blocks x 384 threads, Whh column in registers ----------------
__global__ __launch_bounds__(384) void k_gru(const float* __restrict__ gi,
                                             const float* __restrict__ WhhT,  // [128][384]
                                             const float* __restrict__ bhh,
                                             const float* __restrict__ hG,
                                             float* __restrict__ seqout) {
  int b = blockIdx.x, tid = threadIdx.x;
  int gate = tid >> 7, j = tid & 127;
  __shared__ float h[HH];
  __shared__ float sz[HH], sg[HH];
  float w[HH];
#pragma unroll
  for (int k = 0; k < HH; ++k) w[k] = WhhT[k * 384 + tid];
  float bh = bhh[tid];
  if (tid < HH) h[tid] = hG[b * HH + tid];
  __syncthreads();
  const float* gib = gi + (size_t)b * LL * 384;
  for (int t = 0; t < LL; ++t) {
    float giv = gib[t * 384 + tid];
    float gin = (gate == 0) ? gib[t * 384 + 256 + j] : 0.f;  // wave-uniform branch
    float hj = h[j];
    float g0 = 0.f, g1 = 0.f, g2 = 0.f, g3 = 0.f;
    const float4* h4 = (const float4*)h;
#pragma unroll
    for (int k4 = 0; k4 < HH / 4; ++k4) {
      float4 hv = h4[k4];
      g0 = fmaf(w[4 * k4 + 0], hv.x, g0);
      g1 = fmaf(w[4 * k4 + 1], hv.y, g1);
      g2 = fmaf(w[4 * k4 + 2], hv.z, g2);
      g3 = fmaf(w[4 * k4 + 3], hv.w, g3);
    }
    float g = bh + ((g0 + g1) + (g2 + g3));
    float r = 0.f;
    if (gate == 0) {
      r = 1.f / (1.f + expf(-(giv + g)));
    } else if (gate == 1) {
      sz[j] = 1.f / (1.f + expf(-(giv + g)));
    } else {
      sg[j] = g;
    }
    __syncthreads();
    if (gate == 0) {
      float n = tanhf(gin + r * sg[j]);
      float z = sz[j];
      float hn = (1.f - z) * n + z * hj;
      h[j] = hn;
      seqout[((size_t)b * LL + t) * HH + j] = hn;
    }
    __syncthreads();
  }
}

// ---------------- fused logits ----------------
__global__ __launch_bounds__(256) void k_logits(const float* __restrict__ part1,
                                                const float* __restrict__ part2,
                                                const float* __restrict__ linN_b,
                                                const float* __restrict__ linNf_w,
                                                const float* __restrict__ linNf_b,
                                                const int* __restrict__ bs,
                                                float* __restrict__ logits) {
  int wid = ((blockIdx.x * 256) + threadIdx.x) >> 6;
  int lane = threadIdx.x & 63;
  if (wid >= NN) return;
  int n = wid;
  int b = bs[n];
  float p2a = part2[n * HH + lane] + linN_b[lane];
  float p2b = part2[n * HH + 64 + lane] + linN_b[64 + lane];
  float wa = linNf_w[lane], wb = linNf_w[64 + lane];
  const float* p1 = part1 + (size_t)b * LL * HH;
  float bf = linNf_b[0];
  for (int l = 0; l < LL; ++l) {
    float v = fmaxf(p1[l * HH + lane] + p2a, 0.f) * wa +
              fmaxf(p1[l * HH + 64 + lane] + p2b, 0.f) * wb;
#pragma unroll
    for (int off = 32; off > 0; off >>= 1) v += __shfl_down(v, off);
    if (lane == 0) logits[n * LL + l] = v + bf;
  }
}

// ---------------- segment softmax ----------------
__global__ __launch_bounds__(64) void k_softmax(const float* __restrict__ logits,
                                                const int* __restrict__ bptr,
                                                const int* __restrict__ bnodes,
                                                float* __restrict__ outN) {
  int b = blockIdx.x / LL, l = blockIdx.x % LL;
  int lane = threadIdx.x;
  int i0 = bptr[b], i1 = bptr[b + 1];
  float m = -1e30f;
  for (int i = i0 + lane; i < i1; i += 64) m = fmaxf(m, logits[bnodes[i] * LL + l]);
#pragma unroll
  for (int off = 32; off > 0; off >>= 1) m = fmaxf(m, __shfl_xor(m, off));
  float s = 0.f;
  for (int i = i0 + lane; i < i1; i += 64) s += expf(logits[bnodes[i] * LL + l] - m);
#pragma unroll
  for (int off = 32; off > 0; off >>= 1) s += __shfl_xor(s, off);
  float inv = 1.f / s;
  for (int i = i0 + lane; i < i1; i += 64) {
    int n = bnodes[i];
    outN[n * LL + l] = expf(logits[n * LL + l] - m) * inv;
  }
}

// ---------------- host ----------------
extern "C" void kernel_launch(void* const* d_in, const int* in_sizes, int n_in,
                              void* d_out, int out_size, void* d_ws, size_t ws_size,
                              hipStream_t stream) {
  const int* nodeTypes = (const int*)d_in[0];
  const int* esrc = (const int*)d_in[1];
  const int* edst = esrc + NE;
  const int* erel = (const int*)d_in[2];
  const int* bs = (const int*)d_in[3];
  const float* seqin = (const float*)d_in[4];
  const int* actin = (const int*)d_in[7];
  const float* embN = (const float*)d_in[8];
  const float* embA = (const float*)d_in[9];
  const float* rgcnW = (const float*)d_in[10];
  const float* rgcnRoot = (const float*)d_in[11];
  const float* rgcnB = (const float*)d_in[12];
  const float* Wih = (const float*)d_in[13];
  const float* Whh = (const float*)d_in[14];
  const float* bih = (const float*)d_in[15];
  const float* bhh = (const float*)d_in[16];
  const float* linA_w = (const float*)d_in[17];
  const float* linA_b = (const float*)d_in[18];
  const float* linAf_w = (const float*)d_in[19];
  const float* linAf_b = (const float*)d_in[20];
  const float* linN_w = (const float*)d_in[21];
  const float* linN_b = (const float*)d_in[22];
  const float* linNf_w = (const float*)d_in[23];
  const float* linNf_b = (const float*)d_in[24];
  const float* fin_w = (const float*)d_in[25];
  const float* fin_b = (const float*)d_in[26];
  const float* finf_w = (const float*)d_in[27];
  const float* finf_b = (const float*)d_in[28];

  float* outA = (float*)d_out;
  float* outNodes = outA + BB * VAx;
  float* outF = outNodes + (size_t)NN * LL;

  char* basep = (char*)d_ws;
  size_t off = 0;
  auto alloc = [&](size_t bytes) -> void* {
    void* p = basep + off;
    off = (off + bytes + 255) & ~(size_t)255;
    return p;
  };

  unsigned int* x = (unsigned int*)alloc(sizeof(unsigned int) * NN * 64);   // bf16 pairs
  unsigned int* x2 = (unsigned int*)alloc(sizeof(unsigned int) * NN * 64);  // bf16 pairs
  float* hG = (float*)alloc(sizeof(float) * BB * HH);
  unsigned short* wcatT = (unsigned short*)alloc(sizeof(unsigned short) * HH * KC);
  unsigned short* linN2bt = (unsigned short*)alloc(sizeof(unsigned short) * HH * HH);
  float* WihT = (float*)alloc(sizeof(float) * HH * 3 * HH);
  float* WhhT = (float*)alloc(sizeof(float) * HH * 3 * HH);
  float* linAT = (float*)alloc(sizeof(float) * HH * HH);
  float* finT = (float*)alloc(sizeof(float) * HH * HH);
  float* linN1T = (float*)alloc(sizeof(float) * HH * HH);
  float* part = (float*)alloc(sizeof(float) * BB * CHK * 25 * HH);
  float* ig = (float*)alloc(sizeof(float) * BB * LL * HH);
  float* gi = (float*)alloc(sizeof(float) * BB * LL * 3 * HH);
  float* seq = (float*)alloc(sizeof(float) * BB * LL * HH);
  float* part1 = (float*)alloc(sizeof(float) * BB * LL * HH);
  float* part2 = (float*)alloc(sizeof(float) * NN * HH);
  float* logitsB = (float*)alloc(sizeof(float) * NN * LL);
  int* deg = (int*)alloc(sizeof(int) * NN);
  int* indptr = (int*)alloc(sizeof(int) * (NN + 1));
  int* cur = (int*)alloc(sizeof(int) * NN);
  int* esort = (int*)alloc(sizeof(int) * NE);
  int* bcnt = (int*)alloc(sizeof(int) * BB);
  int* bptr = (int*)alloc(sizeof(int) * (BB + 1));
  int* bcur = (int*)alloc(sizeof(int) * BB);
  int* bnodes = (int*)alloc(sizeof(int) * NN);

  size_t remain = (ws_size > off) ? (ws_size - off) : 0;
  int NCk = NN;
  while ((size_t)NCk * KC * 2 > remain && NCk > 100) NCk >>= 1;
  unsigned int* A = (unsigned int*)alloc((size_t)NCk * (KC / 2) * sizeof(unsigned int));

  // ---- prep (1 launch): weight transforms, embed, zero counters ----
  k_prep<<<(PREP_TOTAL + 255) / 256, 256, 0, stream>>>(
      rgcnW, rgcnRoot, wcatT, linN_w, linN2bt, Wih, WihT, Whh, WhhT, linA_w, linAT,
      fin_w, finT, linN1T, nodeTypes, embN, x, deg, bcnt);
  k_count2<<<(NE + 255) / 256, 256, 0, stream>>>(edst, deg, bs, bcnt);
  k_scan2<<<2, 1024, 0, stream>>>(deg, indptr, cur, bcnt, bptr, bcur);
  k_scatter2<<<(NE + 255) / 256, 256, 0, stream>>>(esrc, edst, erel, cur, esort, bs, bcur,
                                                   bnodes);

  // ---- 2 RGCN layers (shared weights), bf16 MFMA ----
  const unsigned int* xin = x;
  unsigned int* xout = x2;
  for (int layer = 0; layer < 2; ++layer) {
    for (int n0 = 0; n0 < NN; n0 += NCk) {
      int nc = NN - n0 < NCk ? NN - n0 : NCk;
      k_agg<<<(nc + 3) / 4, 256, 0, stream>>>(xin, indptr, esort, A, n0, nc);
      k_mgemm<1><<<(nc + 63) / 64, 256, 0, stream>>>(
          (const unsigned short*)A, KC, wcatT, KC, rgcnB,
          (void*)((unsigned short*)xout + (size_t)n0 * HH), nc, KC);
    }
    const unsigned int* t = xin;
    xin = xout;
    xout = (unsigned int*)t;
  }
  const unsigned short* nodeEmb = (const unsigned short*)xin;

  // ---- aggS partial/reduce: produces ig (with SOS) and hG ----
  k_aggS_part<<<BB * CHK, 256, 0, stream>>>(seqin, nodeEmb, bptr, bnodes, part);
  k_aggS_red<<<(BB * 25 * HH + 255) / 256, 256, 0, stream>>>(part, bptr, embA, actin, ig, hG);

  // ---- heads ----
  k_heads<<<2 * BB, HH, 0, stream>>>(hG, linAT, linA_b, linAf_w, linAf_b, finT, fin_b,
                                     finf_w, finf_b, outA, outF);

  // ---- GRU ----
  {
    dim3 g((3 * HH) / 64, (BB * LL) / 64);
    k_gemm<true, false><<<g, 256, 0, stream>>>(ig, HH, WihT, 3 * HH, bih, gi, 3 * HH,
                                               BB * LL, 3 * HH, HH);
  }
  k_gru<<<BB, 384, 0, stream>>>(gi, WhhT, bhh, hG, seq);

  // ---- node logits ----
  {
    dim3 g(HH / 64, (BB * LL) / 64);
    k_gemm<false, false><<<g, 256, 0, stream>>>(seq, HH, linN1T, HH, nullptr, part1, HH,
                                                BB * LL, HH, HH);
  }
  k_mgemm<0><<<(NN + 63) / 64, 256, 0, stream>>>(nodeEmb, HH, linN2bt, HH, nullptr,
                                                 (void*)part2, NN, HH);
  k_logits<<<NN / 4, 256, 0, stream>>>(part1, part2, linN_b, linNf_w, linNf_b, bs, logitsB);
  k_softmax<<<BB * LL, 64, 0, stream>>>(logitsB, bptr, bnodes, outNodes);
}